// Round 1
// 793.837 us; speedup vs baseline: 1.0271x; 1.0271x over previous
//
#include <hip/hip_runtime.h>
#include <hip/hip_bf16.h>

typedef __hip_bfloat16 bf16;
typedef unsigned short u16;
typedef unsigned int   u32;

#define B_   2
#define CIN_ 64
#define C_   128
#define H_   64
#define W_   1024
#define HW_  (H_*W_)
#define H2_  32
#define W2_  512
#define HW2_ (H2_*W2_)

typedef __attribute__((ext_vector_type(8))) short bf16x8;
typedef __attribute__((ext_vector_type(4))) float f32x4;

// Transformed bf16 weights (row-major, k-contiguous per co row).
#define OFF_C2  0
#define OFF_C3  73728
#define OFF_C4  221184
#define OFF_C5  286720
#define OFF_C1  335872
#define OFF_PW  344064
#define OFF_LIN 393216
#define WTS_TOT 655360
__device__ __align__(16) u16 g_wts[WTS_TOT];
// Module-owned activation buffers (both batches live).
__device__ __align__(16) u16 g_b1[(size_t)B_*C_*HW_];      // 32 MiB
__device__ __align__(16) u16 g_b2[(size_t)B_*C_*HW_];      // 32 MiB (also holds wn)
__device__ __align__(16) u16 g_b3[(size_t)B_*C_*HW_];      // 32 MiB
__device__ __align__(16) u16 g_y [(size_t)B_*2048*HW2_];   // 128 MiB

__device__ __forceinline__ float bits2f(u16 u){
    u32 x = ((u32)u) << 16; float f; __builtin_memcpy(&f, &x, 4); return f;
}
__device__ __forceinline__ u16 f2bits(float v){
    bf16 h = __float2bfloat16(v); u16 u; __builtin_memcpy(&u, &h, 2); return u;
}
__device__ __forceinline__ u16 load_bf16(const float* p){ return f2bits(*p); }
__device__ __forceinline__ u16 load_bf16(const u16* p){ return *p; }
__device__ __forceinline__ float lrelu(float v){ return v > 0.f ? v : 0.01f*v; }
__device__ __forceinline__ float relu (float v){ return v > 0.f ? v : 0.f; }

// ---------------------------------------------------------------------------
// MFMA tile machinery. Tile M=128 (co) x N=128 (pix), K-step 32.
// A/B LDS rows stride LSTR=40 u16 (+16B pad, odd 16B-granule count).
// ---------------------------------------------------------------------------
#define LSTR 40
#define PSTR 136   // full-K (128) B stride for k_pw3

__device__ __forceinline__ void stage_A(u16* As, const u16* w, int wstr, int col0, int tid)
{
#pragma unroll
    for (int r = 0; r < 2; r++) {
        int e = tid + 256*r;
        int co = e >> 2, ch = e & 3;
        *(uint4*)&As[co*LSTR + ch*8] = *(const uint4*)&w[co*wstr + col0 + ch*8];
    }
}

template<typename TIN>
__device__ __forceinline__ void stage_B_shift(u16* Bs, const TIN* src, int kc, int xbase, int tid)
{
#pragma unroll
    for (int r = 0; r < 16; r++) {
        int e = tid + 256*r;
        int kk = e >> 7, j = e & 127;
        int xx = xbase + j;
        u16 v = 0;
        if ((unsigned)xx < (unsigned)W_) v = load_bf16(&src[(kc*32 + kk)*HW_ + xx]);
        Bs[j*LSTR + kk] = v;
    }
}

template<typename TIN>
__device__ __forceinline__ void stage_B_plain(u16* Bs, const TIN* src, int planeStride, int kc, int tid)
{
#pragma unroll
    for (int r = 0; r < 16; r++) {
        int e = tid + 256*r;
        int kk = e >> 7, j = e & 127;
        Bs[j*LSTR + kk] = load_bf16(&src[(kc*32 + kk)*planeStride + j]);
    }
}

__device__ __forceinline__ void mfma_step_s(const u16* As, const u16* Bs, int bstr, int koff,
                                            int lane, int wm, int wn_, f32x4 acc[4][4])
{
    const int quad = lane >> 4, l15 = lane & 15;
    bf16x8 a[4], b[4];
#pragma unroll
    for (int i = 0; i < 4; i++)
        a[i] = *(const bf16x8*)&As[(wm*64 + i*16 + l15)*LSTR + quad*8];
#pragma unroll
    for (int j = 0; j < 4; j++)
        b[j] = *(const bf16x8*)&Bs[(wn_*64 + j*16 + l15)*bstr + koff + quad*8];
#pragma unroll
    for (int i = 0; i < 4; i++)
#pragma unroll
        for (int j = 0; j < 4; j++)
            acc[i][j] = __builtin_amdgcn_mfma_f32_16x16x32_bf16(a[i], b[j], acc[i][j], 0, 0, 0);
}

__device__ __forceinline__ void mfma_step(const u16* As, const u16* Bs,
                                          int lane, int wm, int wn_, f32x4 acc[4][4])
{
    mfma_step_s(As, Bs, LSTR, 0, lane, wm, wn_, acc);
}

__device__ __forceinline__ void init_bias(f32x4 acc[4][4], const float* bias, int wm, int lane)
{
    const int quad = lane >> 4;
#pragma unroll
    for (int i = 0; i < 4; i++)
#pragma unroll
        for (int r = 0; r < 4; r++) {
            float bv = bias[wm*64 + i*16 + quad*4 + r];
#pragma unroll
            for (int j = 0; j < 4; j++) acc[i][j][r] = bv;
        }
}

// ---------------------------------------------------------------------------
// Conv as shift-decomposed GEMM. grid (512, B_), block 256.
// ---------------------------------------------------------------------------
template<typename TIN, int CI, int KS, int DIL, int PAD>
__global__ __launch_bounds__(256)
void k_conv(const TIN* __restrict__ in0, const u16* __restrict__ wT,
            const float* __restrict__ bias, const float* __restrict__ bns,
            const float* __restrict__ bnb, u16* __restrict__ out0)
{
    __shared__ __align__(16) u16 As[128*LSTR];
    __shared__ __align__(16) u16 Bs[128*LSTR];
    const int tid = threadIdx.x, lane = tid & 63, wave = tid >> 6;
    const int wm = wave & 1, wn_ = wave >> 1;
    const TIN* in = in0 + (size_t)blockIdx.y*CI*HW_;
    u16* out = out0 + (size_t)blockIdx.y*C_*HW_;
    const int pix0 = blockIdx.x * 128;
    const int y = pix0 >> 10, x0 = pix0 & 1023;

    f32x4 acc[4][4];
    init_bias(acc, bias, wm, lane);

    for (int p = 0; p < KS*KS; p++) {
        int dy = (p/KS)*DIL - PAD, dx = (p%KS)*DIL - PAD;
        int yy = y + dy;
        if (yy < 0 || yy >= H_) continue;          // wave-uniform (tile = one row)
        const TIN* src = in + yy*W_;
        for (int kc = 0; kc < CI/32; kc++) {
            stage_A(As, wT + p*128*CI, CI, kc*32, tid);
            stage_B_shift(Bs, src, kc, x0 + dx, tid);
            __syncthreads();
            mfma_step(As, Bs, lane, wm, wn_, acc);
            __syncthreads();
        }
    }
    const int quad = lane >> 4, l15 = lane & 15;
#pragma unroll
    for (int i = 0; i < 4; i++)
#pragma unroll
        for (int r = 0; r < 4; r++) {
            int co = wm*64 + i*16 + quad*4 + r;
            float ss = bns[co], tt = bnb[co];
#pragma unroll
            for (int j = 0; j < 4; j++) {
                float v = lrelu(acc[i][j][r]) * ss + tt;
                out[co*HW_ + pix0 + wn_*64 + j*16 + l15] = f2bits(v);
            }
        }
}

// ---------------------------------------------------------------------------
// resA = bn3(lrelu(c5_w@[A1;A2;A3] + c5_b)) + lrelu(c1_w@x + c1_b)  (fp32 out)
// ---------------------------------------------------------------------------
__global__ __launch_bounds__(256)
void k_resA(const float* __restrict__ x0, const u16* __restrict__ a10,
            const u16* __restrict__ a20, const u16* __restrict__ a30,
            const u16* __restrict__ wc1, const float* __restrict__ c1b,
            const u16* __restrict__ wc5, const float* __restrict__ c5b,
            const float* __restrict__ s3, const float* __restrict__ b3,
            float* __restrict__ out0)
{
    __shared__ __align__(16) u16 As[128*LSTR];
    __shared__ __align__(16) u16 Bs[128*LSTR];
    const int tid = threadIdx.x, lane = tid & 63, wave = tid >> 6;
    const int wm = wave & 1, wn_ = wave >> 1;
    const int b = blockIdx.y;
    const float* x = x0 + (size_t)b*CIN_*HW_;
    const u16* aa[3] = { a10 + (size_t)b*C_*HW_, a20 + (size_t)b*C_*HW_, a30 + (size_t)b*C_*HW_ };
    float* out = out0 + (size_t)b*C_*HW_;
    const int pix0 = blockIdx.x * 128;
    const int quad = lane >> 4, l15 = lane & 15;

    // shortcut: K=64 over fp32 x
    f32x4 acc[4][4];
    init_bias(acc, c1b, wm, lane);
    for (int kc = 0; kc < 2; kc++) {
        stage_A(As, wc1, 64, kc*32, tid);
        stage_B_plain(Bs, x + pix0, HW_, kc, tid);
        __syncthreads();
        mfma_step(As, Bs, lane, wm, wn_, acc);
        __syncthreads();
    }
    float sc[4][4][4];
#pragma unroll
    for (int i = 0; i < 4; i++)
#pragma unroll
        for (int j = 0; j < 4; j++)
#pragma unroll
            for (int r = 0; r < 4; r++) sc[i][j][r] = lrelu(acc[i][j][r]);

    // main: K=384 over [A1;A2;A3]
    init_bias(acc, c5b, wm, lane);
    for (int s = 0; s < 3; s++) {
        const u16* src = aa[s];
        for (int kc = 0; kc < 4; kc++) {
            stage_A(As, wc5, 384, s*128 + kc*32, tid);
            stage_B_plain(Bs, src + pix0, HW_, kc, tid);
            __syncthreads();
            mfma_step(As, Bs, lane, wm, wn_, acc);
            __syncthreads();
        }
    }
#pragma unroll
    for (int i = 0; i < 4; i++)
#pragma unroll
        for (int r = 0; r < 4; r++) {
            int co = wm*64 + i*16 + quad*4 + r;
            float ss = s3[co], tt = b3[co];
#pragma unroll
            for (int j = 0; j < 4; j++) {
                float v = lrelu(acc[i][j][r]) * ss + tt + sc[i][j][r];
                out[co*HW_ + pix0 + wn_*64 + j*16 + l15] = v;
            }
        }
}

// ---------------------------------------------------------------------------
// Fused 3-layer pointwise MLP: h = relu(bn(W3 relu(bn(W2 relu(bn(W1 resA)))))).
// One block owns 128 pixels end-to-end; inter-layer activations in LDS.
// ---------------------------------------------------------------------------
__global__ __launch_bounds__(256)
void k_pw3(const float* __restrict__ in0, const u16* __restrict__ w,
           const float* __restrict__ pb, const float* __restrict__ ps,
           const float* __restrict__ pbb, u16* __restrict__ out0)
{
    __shared__ __align__(16) u16 As[128*LSTR];
    __shared__ __align__(16) u16 B0[128*PSTR];
    __shared__ __align__(16) u16 B1[128*PSTR];
    const int tid = threadIdx.x, lane = tid & 63, wave = tid >> 6;
    const int wm = wave & 1, wn_ = wave >> 1;
    const int b = blockIdx.y;
    const float* in = in0 + (size_t)b*C_*HW_;
    u16* out = out0 + (size_t)b*C_*HW_;
    const int pix0 = blockIdx.x * 128;
    const int quad = lane >> 4, l15 = lane & 15;

    // Stage B0 [pix][k] from fp32 resA (vector loads along pix, scatter to LDS)
    for (int e = tid; e < 128*32; e += 256) {
        int kk = e >> 5, j4 = (e & 31)*4;
        float4 v = *(const float4*)&in[kk*HW_ + pix0 + j4];
        u16* d = &B0[j4*PSTR + kk];
        d[0]      = f2bits(v.x);
        d[PSTR]   = f2bits(v.y);
        d[2*PSTR] = f2bits(v.z);
        d[3*PSTR] = f2bits(v.w);
    }

    u16* Bc = B0;
    u16* Bn = B1;
#pragma unroll
    for (int L = 0; L < 3; L++) {
        f32x4 acc[4][4];
        init_bias(acc, pb + L*128, wm, lane);
        for (int kc = 0; kc < 4; kc++) {
            stage_A(As, w + L*16384, 128, kc*32, tid);
            __syncthreads();                       // As + (Bc writes) visible
            mfma_step_s(As, Bc, PSTR, kc*32, lane, wm, wn_, acc);
            __syncthreads();                       // done reading As
        }
        const float* ss = ps + L*128;
        const float* tt = pbb + L*128;
        if (L < 2) {
#pragma unroll
            for (int i = 0; i < 4; i++)
#pragma unroll
                for (int r = 0; r < 4; r++) {
                    int co = wm*64 + i*16 + quad*4 + r;
                    float s1 = ss[co], t1 = tt[co];
#pragma unroll
                    for (int j = 0; j < 4; j++) {
                        float v = relu(acc[i][j][r] * s1 + t1);
                        Bn[(wn_*64 + j*16 + l15)*PSTR + co] = f2bits(v);
                    }
                }
            u16* t = Bc; Bc = Bn; Bn = t;
        } else {
#pragma unroll
            for (int i = 0; i < 4; i++)
#pragma unroll
                for (int r = 0; r < 4; r++) {
                    int co = wm*64 + i*16 + quad*4 + r;
                    float s1 = ss[co], t1 = tt[co];
#pragma unroll
                    for (int j = 0; j < 4; j++) {
                        float v = relu(acc[i][j][r] * s1 + t1);
                        out[co*HW_ + pix0 + wn_*64 + j*16 + l15] = f2bits(v);
                    }
                }
        }
    }
}

// ---------------------------------------------------------------------------
// Linear head GEMM: resB = relu(bn(lin_w @ y + lin_b)).  K=2048.
// ---------------------------------------------------------------------------
__global__ __launch_bounds__(256)
void k_lin(const u16* __restrict__ in0, const u16* __restrict__ w,
           const float* __restrict__ bias, const float* __restrict__ bns,
           const float* __restrict__ bnb, float* __restrict__ out0)
{
    __shared__ __align__(16) u16 As[128*LSTR];
    __shared__ __align__(16) u16 Bs[128*LSTR];
    const int tid = threadIdx.x, lane = tid & 63, wave = tid >> 6;
    const int wm = wave & 1, wn_ = wave >> 1;
    const u16* in = in0 + (size_t)blockIdx.y*2048*HW2_;
    float* out = out0 + (size_t)blockIdx.y*C_*HW2_;
    const int pix0 = blockIdx.x * 128;

    f32x4 acc[4][4];
    init_bias(acc, bias, wm, lane);

    for (int kc = 0; kc < 64; kc++) {
        stage_A(As, w, 2048, kc*32, tid);
        stage_B_plain(Bs, in + pix0, HW2_, kc, tid);
        __syncthreads();
        mfma_step(As, Bs, lane, wm, wn_, acc);
        __syncthreads();
    }
    const int quad = lane >> 4, l15 = lane & 15;
#pragma unroll
    for (int i = 0; i < 4; i++)
#pragma unroll
        for (int r = 0; r < 4; r++) {
            int co = wm*64 + i*16 + quad*4 + r;
            float ss = bns[co], tt = bnb[co];
#pragma unroll
            for (int j = 0; j < 4; j++) {
                float v = relu(acc[i][j][r] * ss + tt);
                out[co*HW2_ + pix0 + wn_*64 + j*16 + l15] = v;
            }
        }
}

// ---------------------------------------------------------------------------
// WeightNet: xyz fp32 -> bf16 [16,25,H2,W2] per batch.
// ---------------------------------------------------------------------------
__global__ __launch_bounds__(256)
void wn_kernel(const float* __restrict__ xyz0,
               const float* __restrict__ w1w, const float* __restrict__ w1b,
               const float* __restrict__ w2w, const float* __restrict__ w2b,
               const float* __restrict__ w3w, const float* __restrict__ w3b,
               const float* __restrict__ s1, const float* __restrict__ bb1,
               const float* __restrict__ s2, const float* __restrict__ bb2,
               const float* __restrict__ s3, const float* __restrict__ bb3,
               u16* __restrict__ out0)
{
    const float* xyz = xyz0 + (size_t)blockIdx.y*3*HW_;
    u16* out = out0 + (size_t)blockIdx.y*400*HW2_;
    int idx = blockIdx.x*256 + threadIdx.x;
    int j = idx & (W2_-1); int t = idx >> 9;
    int i = t & (H2_-1);   int k = t >> 5;
    int kh = k / 5, kw = k - kh*5;
    int yy = 2*i + kh - 2, xx = 2*j + kw - 2;
    bool inr = (yy >= 0 && yy < H_ && xx >= 0 && xx < W_);

    float g[3];
#pragma unroll
    for (int c = 0; c < 3; c++) {
        float ctr = xyz[c*HW_ + (2*i)*W_ + 2*j];
        float v = inr ? xyz[c*HW_ + yy*W_ + xx] : 0.f;
        g[c] = v - ctr;
    }
    float a1[8];
#pragma unroll
    for (int n = 0; n < 8; n++) {
        float v = w1b[n];
#pragma unroll
        for (int c = 0; c < 3; c++) v += w1w[n*3 + c] * g[c];
        a1[n] = relu(v * s1[n] + bb1[n]);
    }
    float a2[8];
#pragma unroll
    for (int n = 0; n < 8; n++) {
        float v = w2b[n];
#pragma unroll
        for (int m = 0; m < 8; m++) v += w2w[n*8 + m] * a1[m];
        a2[n] = relu(v * s2[n] + bb2[n]);
    }
#pragma unroll
    for (int n = 0; n < 16; n++) {
        float v = w3b[n];
#pragma unroll
        for (int m = 0; m < 8; m++) v += w3w[n*8 + m] * a2[m];
        v = relu(v * s3[n] + bb3[n]);
        out[(n*25 + k)*HW2_ + i*W2_ + j] = f2bits(v);
    }
}

// ---------------------------------------------------------------------------
// y[(c*16+n)][pix] = sum_k unf(h)[c][k][pix] * wn[n][k][pix]   (bf16 out)
// grid (32 i2 * 8 jt * 2 cch, B_), block 512: thread = (n, 2 j's), 64 c/block.
// h slab cached in LDS as f32 (unpack amortized across the 16 n's).
// Slab row layout: [2 pad][144 f32], stride 148 -> all float4 reads 16B-aligned,
// all float2 fill writes 8B-aligned.  Row xi=0 corresponds to xs = 2*j0-8.
// ---------------------------------------------------------------------------
__global__ __launch_bounds__(512)
void k_ycompute(const u16* __restrict__ h0, const u16* __restrict__ wn0,
                u16* __restrict__ yd0)
{
    __shared__ __align__(16) float slab[40*148];   // 8 cc * 5 rr rows, 23.7 KB
    const int tid = threadIdx.x;
    const int bx = blockIdx.x;
    const int cch2 = bx & 1;                       // 64-channel half
    const int j0  = ((bx >> 1) & 7) * 64;
    const int i2  = bx >> 4;
    const int b   = blockIdx.y;
    const u16* h  = h0  + (size_t)b*C_*HW_;
    const u16* wn = wn0 + (size_t)b*400*HW2_;
    u16* yd = yd0 + (size_t)b*2048*HW2_;
    const int n = tid >> 5, jg2 = (tid & 31) * 2;  // 2 output pixels / thread

    // wn for this thread's (n, 2 pixels): 25 taps, f32 in regs (50 VGPR)
    float wnreg[25][2];
    {
        const u16* wb = wn + (n*25)*HW2_ + i2*W2_ + j0 + jg2;
#pragma unroll
        for (int k = 0; k < 25; k++) {
            u32 t = *(const u32*)(wb + k*HW2_);
            wnreg[k][0] = bits2f((u16)(t & 0xffff));
            wnreg[k][1] = bits2f((u16)(t >> 16));
        }
    }

    const int c0beg = cch2*64;
    for (int c0 = c0beg; c0 < c0beg + 64; c0 += 8) {
        __syncthreads();                           // prev compute done with slab
        // Fill: 8 cc x 5 rr x 18 uint4-groups; fast path = uint4 load + f32 unpack
        for (int e = tid; e < 720; e += 512) {
            int cc = e / 90, rem = e - cc*90;
            int rr = rem / 18, g = rem - rr*18;
            int yy = 2*i2 + rr - 2;
            int xs0 = 2*j0 - 8 + 8*g;              // 16B-aligned global offset
            float f[8];
            if ((unsigned)yy < (unsigned)H_ && (unsigned)xs0 <= (unsigned)(W_-8)) {
                uint4 v = *(const uint4*)&h[(c0+cc)*HW_ + yy*W_ + xs0];
                f[0] = bits2f((u16)(v.x & 0xffff)); f[1] = bits2f((u16)(v.x >> 16));
                f[2] = bits2f((u16)(v.y & 0xffff)); f[3] = bits2f((u16)(v.y >> 16));
                f[4] = bits2f((u16)(v.z & 0xffff)); f[5] = bits2f((u16)(v.z >> 16));
                f[6] = bits2f((u16)(v.w & 0xffff)); f[7] = bits2f((u16)(v.w >> 16));
            } else if ((unsigned)yy < (unsigned)H_) {
#pragma unroll
                for (int m = 0; m < 8; m++) {
                    int xs = xs0 + m;
                    f[m] = ((unsigned)xs < (unsigned)W_)
                         ? bits2f(h[(c0+cc)*HW_ + yy*W_ + xs]) : 0.f;
                }
            } else {
#pragma unroll
                for (int m = 0; m < 8; m++) f[m] = 0.f;
            }
            float* d = &slab[(cc*5 + rr)*148 + 2 + 8*g];
            *(float2*)(d+0) = make_float2(f[0], f[1]);
            *(float2*)(d+2) = make_float2(f[2], f[3]);
            *(float2*)(d+4) = make_float2(f[4], f[5]);
            *(float2*)(d+6) = make_float2(f[6], f[7]);
        }
        __syncthreads();
#pragma unroll 2
        for (int cc = 0; cc < 8; cc++) {
            float yv0 = 0.f, yv1 = 0.f;
#pragma unroll
            for (int rr = 0; rr < 5; rr++) {
                // xi = 6 + 2*jg2 + (2*jj + kw); read f[0..6] via 2 aligned float4
                const float* fr = &slab[(cc*5 + rr)*148 + 8 + 2*jg2];
                float4 A  = *(const float4*)fr;
                float4 Bv = *(const float4*)(fr + 4);
                yv0 += A.x*wnreg[rr*5+0][0] + A.y*wnreg[rr*5+1][0]
                     + A.z*wnreg[rr*5+2][0] + A.w*wnreg[rr*5+3][0]
                     + Bv.x*wnreg[rr*5+4][0];
                yv1 += A.z*wnreg[rr*5+0][1] + A.w*wnreg[rr*5+1][1]
                     + Bv.x*wnreg[rr*5+2][1] + Bv.y*wnreg[rr*5+3][1]
                     + Bv.z*wnreg[rr*5+4][1];
            }
            int m = (c0 + cc)*16 + n;
            u16* yp = yd + (size_t)m*HW2_ + i2*W2_ + j0 + jg2;
            *(u32*)yp = (u32)f2bits(yv0) | ((u32)f2bits(yv1) << 16);
        }
    }
}

// ---------------------------------------------------------------------------
// Weight transform: fp32 -> bf16 g_wts (k-contiguous layouts).
// ---------------------------------------------------------------------------
__global__ __launch_bounds__(256)
void k_wtrans(const float* __restrict__ c2w, const float* __restrict__ c3w,
              const float* __restrict__ c4w, const float* __restrict__ c5w,
              const float* __restrict__ c1w, const float* __restrict__ pw,
              const float* __restrict__ linw)
{
    int i = blockIdx.x*256 + threadIdx.x;
    if (i >= WTS_TOT) return;
    float v;
    if (i < OFF_C3) {
        int p = i / 8192, rem = i - p*8192;
        int co = rem >> 6, ci = rem & 63;
        v = c2w[(co*64 + ci)*9 + p];
    } else if (i < OFF_C4) {
        int t = i - OFF_C3;
        int p = t / 16384, rem = t - p*16384;
        int co = rem >> 7, ci = rem & 127;
        v = c3w[(co*128 + ci)*9 + p];
    } else if (i < OFF_C5) {
        int t = i - OFF_C4;
        int p = t / 16384, rem = t - p*16384;
        int co = rem >> 7, ci = rem & 127;
        v = c4w[(co*128 + ci)*4 + p];
    } else if (i < OFF_C1)  v = c5w[i - OFF_C5];
    else if (i < OFF_PW)    v = c1w[i - OFF_C1];
    else if (i < OFF_LIN)   v = pw[i - OFF_PW];
    else                    v = linw[i - OFF_LIN];
    g_wts[i] = f2bits(v);
}

// ---------------------------------------------------------------------------
extern "C" void kernel_launch(void* const* d_in, const int* in_sizes, int n_in,
                              void* d_out, int out_size, void* d_ws, size_t ws_size,
                              hipStream_t stream)
{
    const float* x     = (const float*)d_in[0];
    const float* xyz   = (const float*)d_in[1];
    const float* c1_w  = (const float*)d_in[2];
    const float* c1_b  = (const float*)d_in[3];
    const float* c2_w  = (const float*)d_in[4];
    const float* c2_b  = (const float*)d_in[5];
    const float* c3_w  = (const float*)d_in[6];
    const float* c3_b  = (const float*)d_in[7];
    const float* c4_w  = (const float*)d_in[8];
    const float* c4_b  = (const float*)d_in[9];
    const float* c5_w  = (const float*)d_in[10];
    const float* c5_b  = (const float*)d_in[11];
    const float* rbn_s = (const float*)d_in[12];
    const float* rbn_b = (const float*)d_in[13];
    const float* p_w   = (const float*)d_in[14];
    const float* p_b   = (const float*)d_in[15];
    const float* pbn_s = (const float*)d_in[16];
    const float* pbn_b = (const float*)d_in[17];
    const float* lin_w = (const float*)d_in[18];
    const float* lin_b = (const float*)d_in[19];
    const float* w1_w  = (const float*)d_in[20];
    const float* w1_b  = (const float*)d_in[21];
    const float* w2_w  = (const float*)d_in[22];
    const float* w2_b  = (const float*)d_in[23];
    const float* w3_w  = (const float*)d_in[24];
    const float* w3_b  = (const float*)d_in[25];
    const float* wbn1_s = (const float*)d_in[26];
    const float* wbn1_b = (const float*)d_in[27];
    const float* wbn2_s = (const float*)d_in[28];
    const float* wbn2_b = (const float*)d_in[29];
    const float* wbn3_s = (const float*)d_in[30];
    const float* wbn3_b = (const float*)d_in[31];

    float* outB = (float*)d_out;                     // [2,128,32,512] fp32
    float* outA = outB + (size_t)B_*C_*HW2_;         // [2,128,64,1024] fp32

    u16 *wts, *b1, *b2, *b3, *yb;
    { void* p; hipGetSymbolAddress(&p, HIP_SYMBOL(g_wts)); wts = (u16*)p; }
    { void* p; hipGetSymbolAddress(&p, HIP_SYMBOL(g_b1));  b1  = (u16*)p; }
    { void* p; hipGetSymbolAddress(&p, HIP_SYMBOL(g_b2));  b2  = (u16*)p; }
    { void* p; hipGetSymbolAddress(&p, HIP_SYMBOL(g_b3));  b3  = (u16*)p; }
    { void* p; hipGetSymbolAddress(&p, HIP_SYMBOL(g_y));   yb  = (u16*)p; }

    dim3 blk(256);

    k_wtrans<<<dim3((WTS_TOT + 255)/256), blk, 0, stream>>>(c2_w, c3_w, c4_w, c5_w,
                                                            c1_w, p_w, lin_w);
    k_conv<float,64,3,1,1><<<dim3(512, B_), blk, 0, stream>>>(x, wts+OFF_C2, c2_b,
                                                              rbn_s, rbn_b, b1);
    k_conv<u16,128,3,2,2><<<dim3(512, B_), blk, 0, stream>>>(b1, wts+OFF_C3, c3_b,
                                                             rbn_s+128, rbn_b+128, b2);
    k_conv<u16,128,2,2,1><<<dim3(512, B_), blk, 0, stream>>>(b2, wts+OFF_C4, c4_b,
                                                             rbn_s+256, rbn_b+256, b3);
    k_resA<<<dim3(512, B_), blk, 0, stream>>>(x, b1, b2, b3, wts+OFF_C1, c1_b,
                                              wts+OFF_C5, c5_b, rbn_s+384, rbn_b+384, outA);
    k_pw3<<<dim3(512, B_), blk, 0, stream>>>(outA, wts+OFF_PW, p_b, pbn_s, pbn_b, b1);
    wn_kernel<<<dim3(1600, B_), blk, 0, stream>>>(xyz, w1_w, w1_b, w2_w, w2_b, w3_w, w3_b,
                                                  wbn1_s, wbn1_b, wbn2_s, wbn2_b,
                                                  wbn3_s, wbn3_b, b2);
    k_ycompute<<<dim3(512, B_), dim3(512), 0, stream>>>(b1, b2, yb);
    k_lin<<<dim3(128, B_), blk, 0, stream>>>(yb, wts+OFF_LIN, lin_b,
                                             pbn_s+384, pbn_b+384, outB);
}

// Round 2
// 677.703 us; speedup vs baseline: 1.2031x; 1.1714x over previous
//
#include <hip/hip_runtime.h>
#include <hip/hip_bf16.h>

typedef __hip_bfloat16 bf16;
typedef unsigned short u16;
typedef unsigned int   u32;

#define B_   2
#define CIN_ 64
#define C_   128
#define H_   64
#define W_   1024
#define HW_  (H_*W_)
#define H2_  32
#define W2_  512
#define HW2_ (H2_*W2_)

typedef __attribute__((ext_vector_type(8))) short bf16x8;
typedef __attribute__((ext_vector_type(4))) float f32x4;

// Transformed bf16 weights (row-major, k-contiguous per co row).
#define OFF_C2  0
#define OFF_C3  73728
#define OFF_C4  221184
#define OFF_C5  286720
#define OFF_C1  335872
#define OFF_PW  344064
#define OFF_LIN 393216
#define WTS_TOT 655360
__device__ __align__(16) u16 g_wts[WTS_TOT];
// Module-owned activation buffers (both batches live).
// b1/b2/b3 hold conv-pipeline activations in PX-MAJOR [hw][128] bf16 layout.
// (b1 later reused for h in [c][hw]; b2 later reused for wn.)
__device__ __align__(16) u16 g_b1[(size_t)B_*C_*HW_];      // 32 MiB
__device__ __align__(16) u16 g_b2[(size_t)B_*C_*HW_];      // 32 MiB
__device__ __align__(16) u16 g_b3[(size_t)B_*C_*HW_];      // 32 MiB
__device__ __align__(16) u16 g_y [(size_t)B_*2048*HW2_];   // 128 MiB (early: xb [hw][64])

__device__ __forceinline__ float bits2f(u16 u){
    u32 x = ((u32)u) << 16; float f; __builtin_memcpy(&f, &x, 4); return f;
}
__device__ __forceinline__ u16 f2bits(float v){
    bf16 h = __float2bfloat16(v); u16 u; __builtin_memcpy(&u, &h, 2); return u;
}
__device__ __forceinline__ float lrelu(float v){ return v > 0.f ? v : 0.01f*v; }
__device__ __forceinline__ float relu (float v){ return v > 0.f ? v : 0.f; }

// ---------------------------------------------------------------------------
// MFMA tile machinery. Tile M=128 (co) x N=128 (pix), K-step 32.
// A/B LDS rows stride LSTR=40 u16 (+16B pad, odd 16B-granule count).
// ---------------------------------------------------------------------------
#define LSTR 40
#define PSTR 136   // full-K (128) B stride for k_pw3
#define TSTR 136   // epilogue transpose tile stride (16B-aligned rows)

__device__ __forceinline__ void stage_A(u16* As, const u16* w, int wstr, int col0, int tid)
{
#pragma unroll
    for (int r = 0; r < 2; r++) {
        int e = tid + 256*r;
        int co = e >> 2, ch = e & 3;
        *(uint4*)&As[co*LSTR + ch*8] = *(const uint4*)&w[co*wstr + col0 + ch*8];
    }
}

// B-tile staging from px-major activations: row j = pixel, k = channels
// (k-contiguous in memory -> pure vector copy, no transpose).
__device__ __forceinline__ void stage_B_pm(u16* Bs, const u16* src, int rowStride,
                                           int kc, int tid)
{
#pragma unroll
    for (int r = 0; r < 2; r++) {
        int e = tid + 256*r;
        int j = e >> 2, g = e & 3;
        *(uint4*)&Bs[j*LSTR + g*8] =
            *(const uint4*)&src[(size_t)j*rowStride + kc*32 + g*8];
    }
}

__device__ __forceinline__ void mfma_step_s(const u16* As, const u16* Bs, int bstr, int koff,
                                            int lane, int wm, int wn_, f32x4 acc[4][4])
{
    const int quad = lane >> 4, l15 = lane & 15;
    bf16x8 a[4], b[4];
#pragma unroll
    for (int i = 0; i < 4; i++)
        a[i] = *(const bf16x8*)&As[(wm*64 + i*16 + l15)*LSTR + quad*8];
#pragma unroll
    for (int j = 0; j < 4; j++)
        b[j] = *(const bf16x8*)&Bs[(wn_*64 + j*16 + l15)*bstr + koff + quad*8];
#pragma unroll
    for (int i = 0; i < 4; i++)
#pragma unroll
        for (int j = 0; j < 4; j++)
            acc[i][j] = __builtin_amdgcn_mfma_f32_16x16x32_bf16(a[i], b[j], acc[i][j], 0, 0, 0);
}

__device__ __forceinline__ void mfma_step(const u16* As, const u16* Bs,
                                          int lane, int wm, int wn_, f32x4 acc[4][4])
{
    mfma_step_s(As, Bs, LSTR, 0, lane, wm, wn_, acc);
}

__device__ __forceinline__ void init_bias(f32x4 acc[4][4], const float* bias, int wm, int lane)
{
    const int quad = lane >> 4;
#pragma unroll
    for (int i = 0; i < 4; i++)
#pragma unroll
        for (int r = 0; r < 4; r++) {
            float bv = bias[wm*64 + i*16 + quad*4 + r];
#pragma unroll
            for (int j = 0; j < 4; j++) acc[i][j][r] = bv;
        }
}

// ---------------------------------------------------------------------------
// x transpose: fp32 [64][HW] -> bf16 [HW][64] (enables vector B-staging in
// c2 conv and resA shortcut). grid (512, B_), block 256.
// ---------------------------------------------------------------------------
#define XTS 70
__global__ __launch_bounds__(256)
void k_xtrans(const float* __restrict__ x0, u16* __restrict__ xb0)
{
    __shared__ __align__(16) u16 T[128*XTS];
    const int tid = threadIdx.x;
    const float* x = x0 + (size_t)blockIdx.y*CIN_*HW_;
    u16* xb = xb0 + (size_t)blockIdx.y*HW_*CIN_;
    const int pix0 = blockIdx.x * 128;
#pragma unroll
    for (int r = 0; r < 8; r++) {
        int e = tid + 256*r;               // 2048 items: 64 c x 32 px-groups
        int c = e >> 5, p4 = (e & 31)*4;
        float4 v = *(const float4*)&x[(size_t)c*HW_ + pix0 + p4];
        T[(p4+0)*XTS + c] = f2bits(v.x);
        T[(p4+1)*XTS + c] = f2bits(v.y);
        T[(p4+2)*XTS + c] = f2bits(v.z);
        T[(p4+3)*XTS + c] = f2bits(v.w);
    }
    __syncthreads();
#pragma unroll
    for (int r = 0; r < 4; r++) {
        int e = tid + 256*r;               // 1024 granules: 128 px x 8
        int p = e >> 3, g = e & 7;
        // rows are XTS*2=140B apart; granule addr 8B-aligned -> copy as 2 uint2
        const u16* s = &T[p*XTS + g*8];
        u16* d = &xb[(size_t)(pix0+p)*CIN_ + g*8];
        *(uint2*)&d[0] = *(const uint2*)&s[0];
        *(uint2*)&d[4] = *(const uint2*)&s[4];
    }
}

// ---------------------------------------------------------------------------
// Conv as shift-decomposed GEMM over px-major activations.
// grid (512, B_), block 256.  in: [hw][CI] bf16, out: [hw][128] bf16.
// ---------------------------------------------------------------------------
template<int CI, int KS, int DIL, int PAD>
__global__ __launch_bounds__(256)
void k_conv(const u16* __restrict__ in0, const u16* __restrict__ wT,
            const float* __restrict__ bias, const float* __restrict__ bns,
            const float* __restrict__ bnb, u16* __restrict__ out0)
{
    __shared__ __align__(16) u16 S[128*TSTR];     // 34.8 KB; As|Bs, reused as T
    u16* As = S;
    u16* Bs = S + 128*LSTR;
    const int tid = threadIdx.x, lane = tid & 63, wave = tid >> 6;
    const int wm = wave & 1, wn_ = wave >> 1;
    const u16* in = in0 + (size_t)blockIdx.y*HW_*CI;
    u16* out = out0 + (size_t)blockIdx.y*HW_*C_;
    const int pix0 = blockIdx.x * 128;
    const int y = pix0 >> 10, x0 = pix0 & 1023;

    f32x4 acc[4][4];
    init_bias(acc, bias, wm, lane);

    for (int p = 0; p < KS*KS; p++) {
        int dy = (p/KS)*DIL - PAD, dx = (p%KS)*DIL - PAD;
        int yy = y + dy;
        if (yy < 0 || yy >= H_) continue;          // wave-uniform (tile = one row)
        const u16* srow = in + (size_t)yy*W_*CI;
        for (int kc = 0; kc < CI/32; kc++) {
            stage_A(As, wT + p*128*CI, CI, kc*32, tid);
#pragma unroll
            for (int r = 0; r < 2; r++) {
                int e = tid + 256*r;
                int j = e >> 2, g = e & 3;
                int xx = x0 + dx + j;
                uint4 v = make_uint4(0u, 0u, 0u, 0u);
                if ((unsigned)xx < (unsigned)W_)
                    v = *(const uint4*)&srow[(size_t)xx*CI + kc*32 + g*8];
                *(uint4*)&Bs[j*LSTR + g*8] = v;
            }
            __syncthreads();
            mfma_step(As, Bs, lane, wm, wn_, acc);
            __syncthreads();
        }
    }
    // Epilogue: bn+lrelu -> LDS transpose tile [px][co] -> vector px-major store
    const int quad = lane >> 4, l15 = lane & 15;
    u16* T = S;
#pragma unroll
    for (int i = 0; i < 4; i++)
#pragma unroll
        for (int r = 0; r < 4; r++) {
            int co = wm*64 + i*16 + quad*4 + r;
            float ss = bns[co], tt = bnb[co];
#pragma unroll
            for (int j = 0; j < 4; j++) {
                float v = lrelu(acc[i][j][r]) * ss + tt;
                T[(wn_*64 + j*16 + l15)*TSTR + co] = f2bits(v);
            }
        }
    __syncthreads();
#pragma unroll
    for (int r = 0; r < 8; r++) {
        int e = tid + 256*r;
        int px = e >> 4, g = e & 15;
        *(uint4*)&out[(size_t)(pix0+px)*C_ + g*8] = *(const uint4*)&T[px*TSTR + g*8];
    }
}

// ---------------------------------------------------------------------------
// resA = bn3(lrelu(c5_w@[A1;A2;A3] + c5_b)) + lrelu(c1_w@x + c1_b)  (fp32 out)
// Inputs xb/A1/A2/A3 in px-major layout; output stays [C][HW] fp32 (required).
// ---------------------------------------------------------------------------
__global__ __launch_bounds__(256)
void k_resA(const u16* __restrict__ xb0, const u16* __restrict__ a10,
            const u16* __restrict__ a20, const u16* __restrict__ a30,
            const u16* __restrict__ wc1, const float* __restrict__ c1b,
            const u16* __restrict__ wc5, const float* __restrict__ c5b,
            const float* __restrict__ s3, const float* __restrict__ b3,
            float* __restrict__ out0)
{
    __shared__ __align__(16) u16 As[128*LSTR];
    __shared__ __align__(16) u16 Bs[128*LSTR];
    const int tid = threadIdx.x, lane = tid & 63, wave = tid >> 6;
    const int wm = wave & 1, wn_ = wave >> 1;
    const int b = blockIdx.y;
    const u16* xb = xb0 + (size_t)b*HW_*CIN_;
    const u16* aa[3] = { a10 + (size_t)b*HW_*C_, a20 + (size_t)b*HW_*C_, a30 + (size_t)b*HW_*C_ };
    float* out = out0 + (size_t)b*C_*HW_;
    const int pix0 = blockIdx.x * 128;
    const int quad = lane >> 4, l15 = lane & 15;

    // shortcut: K=64 over xb
    f32x4 acc[4][4];
    init_bias(acc, c1b, wm, lane);
    for (int kc = 0; kc < 2; kc++) {
        stage_A(As, wc1, 64, kc*32, tid);
        stage_B_pm(Bs, xb + (size_t)pix0*CIN_, CIN_, kc, tid);
        __syncthreads();
        mfma_step(As, Bs, lane, wm, wn_, acc);
        __syncthreads();
    }
    float sc[4][4][4];
#pragma unroll
    for (int i = 0; i < 4; i++)
#pragma unroll
        for (int j = 0; j < 4; j++)
#pragma unroll
            for (int r = 0; r < 4; r++) sc[i][j][r] = lrelu(acc[i][j][r]);

    // main: K=384 over [A1;A2;A3]
    init_bias(acc, c5b, wm, lane);
    for (int s = 0; s < 3; s++) {
        const u16* src = aa[s] + (size_t)pix0*C_;
        for (int kc = 0; kc < 4; kc++) {
            stage_A(As, wc5, 384, s*128 + kc*32, tid);
            stage_B_pm(Bs, src, C_, kc, tid);
            __syncthreads();
            mfma_step(As, Bs, lane, wm, wn_, acc);
            __syncthreads();
        }
    }
#pragma unroll
    for (int i = 0; i < 4; i++)
#pragma unroll
        for (int r = 0; r < 4; r++) {
            int co = wm*64 + i*16 + quad*4 + r;
            float ss = s3[co], tt = b3[co];
#pragma unroll
            for (int j = 0; j < 4; j++) {
                float v = lrelu(acc[i][j][r]) * ss + tt + sc[i][j][r];
                out[co*HW_ + pix0 + wn_*64 + j*16 + l15] = v;
            }
        }
}

// ---------------------------------------------------------------------------
// Fused 3-layer pointwise MLP: h = relu(bn(W3 relu(bn(W2 relu(bn(W1 resA)))))).
// One block owns 128 pixels end-to-end; inter-layer activations in LDS.
// Output h stays channel-major [C][HW] (k_ycompute wants x-contiguous rows).
// ---------------------------------------------------------------------------
__global__ __launch_bounds__(256)
void k_pw3(const float* __restrict__ in0, const u16* __restrict__ w,
           const float* __restrict__ pb, const float* __restrict__ ps,
           const float* __restrict__ pbb, u16* __restrict__ out0)
{
    __shared__ __align__(16) u16 As[128*LSTR];
    __shared__ __align__(16) u16 B0[128*PSTR];
    __shared__ __align__(16) u16 B1[128*PSTR];
    const int tid = threadIdx.x, lane = tid & 63, wave = tid >> 6;
    const int wm = wave & 1, wn_ = wave >> 1;
    const int b = blockIdx.y;
    const float* in = in0 + (size_t)b*C_*HW_;
    u16* out = out0 + (size_t)b*C_*HW_;
    const int pix0 = blockIdx.x * 128;
    const int quad = lane >> 4, l15 = lane & 15;

    // Stage B0 [pix][k] from fp32 resA (vector loads along pix, scatter to LDS)
    for (int e = tid; e < 128*32; e += 256) {
        int kk = e >> 5, j4 = (e & 31)*4;
        float4 v = *(const float4*)&in[kk*HW_ + pix0 + j4];
        u16* d = &B0[j4*PSTR + kk];
        d[0]      = f2bits(v.x);
        d[PSTR]   = f2bits(v.y);
        d[2*PSTR] = f2bits(v.z);
        d[3*PSTR] = f2bits(v.w);
    }

    u16* Bc = B0;
    u16* Bn = B1;
#pragma unroll
    for (int L = 0; L < 3; L++) {
        f32x4 acc[4][4];
        init_bias(acc, pb + L*128, wm, lane);
        for (int kc = 0; kc < 4; kc++) {
            stage_A(As, w + L*16384, 128, kc*32, tid);
            __syncthreads();                       // As + (Bc writes) visible
            mfma_step_s(As, Bc, PSTR, kc*32, lane, wm, wn_, acc);
            __syncthreads();                       // done reading As
        }
        const float* ss = ps + L*128;
        const float* tt = pbb + L*128;
        if (L < 2) {
#pragma unroll
            for (int i = 0; i < 4; i++)
#pragma unroll
                for (int r = 0; r < 4; r++) {
                    int co = wm*64 + i*16 + quad*4 + r;
                    float s1 = ss[co], t1 = tt[co];
#pragma unroll
                    for (int j = 0; j < 4; j++) {
                        float v = relu(acc[i][j][r] * s1 + t1);
                        Bn[(wn_*64 + j*16 + l15)*PSTR + co] = f2bits(v);
                    }
                }
            u16* t = Bc; Bc = Bn; Bn = t;
        } else {
#pragma unroll
            for (int i = 0; i < 4; i++)
#pragma unroll
                for (int r = 0; r < 4; r++) {
                    int co = wm*64 + i*16 + quad*4 + r;
                    float s1 = ss[co], t1 = tt[co];
#pragma unroll
                    for (int j = 0; j < 4; j++) {
                        float v = relu(acc[i][j][r] * s1 + t1);
                        out[co*HW_ + pix0 + wn_*64 + j*16 + l15] = f2bits(v);
                    }
                }
        }
    }
}

// ---------------------------------------------------------------------------
// Linear head GEMM: resB = relu(bn(lin_w @ y + lin_b)).  K=2048.
// y in px-major [hw2][2048] -> vectorized B staging.
// ---------------------------------------------------------------------------
__global__ __launch_bounds__(256)
void k_lin(const u16* __restrict__ in0, const u16* __restrict__ w,
           const float* __restrict__ bias, const float* __restrict__ bns,
           const float* __restrict__ bnb, float* __restrict__ out0)
{
    __shared__ __align__(16) u16 As[128*LSTR];
    __shared__ __align__(16) u16 Bs[128*LSTR];
    const int tid = threadIdx.x, lane = tid & 63, wave = tid >> 6;
    const int wm = wave & 1, wn_ = wave >> 1;
    const u16* in = in0 + (size_t)blockIdx.y*HW2_*2048;
    float* out = out0 + (size_t)blockIdx.y*C_*HW2_;
    const int pix0 = blockIdx.x * 128;

    f32x4 acc[4][4];
    init_bias(acc, bias, wm, lane);

    for (int kc = 0; kc < 64; kc++) {
        stage_A(As, w, 2048, kc*32, tid);
        stage_B_pm(Bs, in + (size_t)pix0*2048, 2048, kc, tid);
        __syncthreads();
        mfma_step(As, Bs, lane, wm, wn_, acc);
        __syncthreads();
    }
    const int quad = lane >> 4, l15 = lane & 15;
#pragma unroll
    for (int i = 0; i < 4; i++)
#pragma unroll
        for (int r = 0; r < 4; r++) {
            int co = wm*64 + i*16 + quad*4 + r;
            float ss = bns[co], tt = bnb[co];
#pragma unroll
            for (int j = 0; j < 4; j++) {
                float v = relu(acc[i][j][r] * ss + tt);
                out[co*HW2_ + pix0 + wn_*64 + j*16 + l15] = v;
            }
        }
}

// ---------------------------------------------------------------------------
// WeightNet: xyz fp32 -> bf16 [16,25,H2,W2] per batch.
// ---------------------------------------------------------------------------
__global__ __launch_bounds__(256)
void wn_kernel(const float* __restrict__ xyz0,
               const float* __restrict__ w1w, const float* __restrict__ w1b,
               const float* __restrict__ w2w, const float* __restrict__ w2b,
               const float* __restrict__ w3w, const float* __restrict__ w3b,
               const float* __restrict__ s1, const float* __restrict__ bb1,
               const float* __restrict__ s2, const float* __restrict__ bb2,
               const float* __restrict__ s3, const float* __restrict__ bb3,
               u16* __restrict__ out0)
{
    const float* xyz = xyz0 + (size_t)blockIdx.y*3*HW_;
    u16* out = out0 + (size_t)blockIdx.y*400*HW2_;
    int idx = blockIdx.x*256 + threadIdx.x;
    int j = idx & (W2_-1); int t = idx >> 9;
    int i = t & (H2_-1);   int k = t >> 5;
    int kh = k / 5, kw = k - kh*5;
    int yy = 2*i + kh - 2, xx = 2*j + kw - 2;
    bool inr = (yy >= 0 && yy < H_ && xx >= 0 && xx < W_);

    float g[3];
#pragma unroll
    for (int c = 0; c < 3; c++) {
        float ctr = xyz[c*HW_ + (2*i)*W_ + 2*j];
        float v = inr ? xyz[c*HW_ + yy*W_ + xx] : 0.f;
        g[c] = v - ctr;
    }
    float a1[8];
#pragma unroll
    for (int n = 0; n < 8; n++) {
        float v = w1b[n];
#pragma unroll
        for (int c = 0; c < 3; c++) v += w1w[n*3 + c] * g[c];
        a1[n] = relu(v * s1[n] + bb1[n]);
    }
    float a2[8];
#pragma unroll
    for (int n = 0; n < 8; n++) {
        float v = w2b[n];
#pragma unroll
        for (int m = 0; m < 8; m++) v += w2w[n*8 + m] * a1[m];
        a2[n] = relu(v * s2[n] + bb2[n]);
    }
#pragma unroll
    for (int n = 0; n < 16; n++) {
        float v = w3b[n];
#pragma unroll
        for (int m = 0; m < 8; m++) v += w3w[n*8 + m] * a2[m];
        v = relu(v * s3[n] + bb3[n]);
        out[(n*25 + k)*HW2_ + i*W2_ + j] = f2bits(v);
    }
}

// ---------------------------------------------------------------------------
// y[px][(c*16+n)] = sum_k unf(h)[c][k][px] * wn[n][k][px]   (bf16, px-major out)
// grid (32 i2 * 8 jt * 2 cch, B_), block 512: thread = (n, 2 j's), 64 c/block.
// h slab cached in LDS as f32 (unpack amortized across the 16 n's).
// ---------------------------------------------------------------------------
__global__ __launch_bounds__(512)
void k_ycompute(const u16* __restrict__ h0, const u16* __restrict__ wn0,
                u16* __restrict__ yd0)
{
    __shared__ __align__(16) float slab[40*148];   // 8 cc * 5 rr rows, 23.7 KB
    const int tid = threadIdx.x;
    const int bx = blockIdx.x;
    const int cch2 = bx & 1;                       // 64-channel half
    const int j0  = ((bx >> 1) & 7) * 64;
    const int i2  = bx >> 4;
    const int b   = blockIdx.y;
    const u16* h  = h0  + (size_t)b*C_*HW_;
    const u16* wn = wn0 + (size_t)b*400*HW2_;
    u16* yd = yd0 + (size_t)b*2048*HW2_;
    const int n = tid >> 5, jg2 = (tid & 31) * 2;  // 2 output pixels / thread

    // wn for this thread's (n, 2 pixels): 25 taps, f32 in regs (50 VGPR)
    float wnreg[25][2];
    {
        const u16* wb = wn + (n*25)*HW2_ + i2*W2_ + j0 + jg2;
#pragma unroll
        for (int k = 0; k < 25; k++) {
            u32 t = *(const u32*)(wb + k*HW2_);
            wnreg[k][0] = bits2f((u16)(t & 0xffff));
            wnreg[k][1] = bits2f((u16)(t >> 16));
        }
    }

    const int c0beg = cch2*64;
    for (int c0 = c0beg; c0 < c0beg + 64; c0 += 8) {
        __syncthreads();                           // prev compute done with slab
        // Fill: 8 cc x 5 rr x 18 uint4-groups; fast path = uint4 load + f32 unpack
        for (int e = tid; e < 720; e += 512) {
            int cc = e / 90, rem = e - cc*90;
            int rr = rem / 18, g = rem - rr*18;
            int yy = 2*i2 + rr - 2;
            int xs0 = 2*j0 - 8 + 8*g;              // 16B-aligned global offset
            float f[8];
            if ((unsigned)yy < (unsigned)H_ && (unsigned)xs0 <= (unsigned)(W_-8)) {
                uint4 v = *(const uint4*)&h[(c0+cc)*HW_ + yy*W_ + xs0];
                f[0] = bits2f((u16)(v.x & 0xffff)); f[1] = bits2f((u16)(v.x >> 16));
                f[2] = bits2f((u16)(v.y & 0xffff)); f[3] = bits2f((u16)(v.y >> 16));
                f[4] = bits2f((u16)(v.z & 0xffff)); f[5] = bits2f((u16)(v.z >> 16));
                f[6] = bits2f((u16)(v.w & 0xffff)); f[7] = bits2f((u16)(v.w >> 16));
            } else if ((unsigned)yy < (unsigned)H_) {
#pragma unroll
                for (int m = 0; m < 8; m++) {
                    int xs = xs0 + m;
                    f[m] = ((unsigned)xs < (unsigned)W_)
                         ? bits2f(h[(c0+cc)*HW_ + yy*W_ + xs]) : 0.f;
                }
            } else {
#pragma unroll
                for (int m = 0; m < 8; m++) f[m] = 0.f;
            }
            float* d = &slab[(cc*5 + rr)*148 + 2 + 8*g];
            *(float2*)(d+0) = make_float2(f[0], f[1]);
            *(float2*)(d+2) = make_float2(f[2], f[3]);
            *(float2*)(d+4) = make_float2(f[4], f[5]);
            *(float2*)(d+6) = make_float2(f[6], f[7]);
        }
        __syncthreads();
#pragma unroll 2
        for (int cc = 0; cc < 8; cc++) {
            float yv0 = 0.f, yv1 = 0.f;
#pragma unroll
            for (int rr = 0; rr < 5; rr++) {
                // xi = 6 + 2*jg2 + (2*jj + kw); read f[0..6] via 2 aligned float4
                const float* fr = &slab[(cc*5 + rr)*148 + 8 + 2*jg2];
                float4 A  = *(const float4*)fr;
                float4 Bv = *(const float4*)(fr + 4);
                yv0 += A.x*wnreg[rr*5+0][0] + A.y*wnreg[rr*5+1][0]
                     + A.z*wnreg[rr*5+2][0] + A.w*wnreg[rr*5+3][0]
                     + Bv.x*wnreg[rr*5+4][0];
                yv1 += A.z*wnreg[rr*5+0][1] + A.w*wnreg[rr*5+1][1]
                     + Bv.x*wnreg[rr*5+2][1] + Bv.y*wnreg[rr*5+3][1]
                     + Bv.z*wnreg[rr*5+4][1];
            }
            int m = (c0 + cc)*16 + n;
            u16* yp = yd + ((size_t)(i2*W2_ + j0 + jg2))*2048 + m;
            yp[0]    = f2bits(yv0);
            yp[2048] = f2bits(yv1);
        }
    }
}

// ---------------------------------------------------------------------------
// Weight transform: fp32 -> bf16 g_wts (k-contiguous layouts).
// ---------------------------------------------------------------------------
__global__ __launch_bounds__(256)
void k_wtrans(const float* __restrict__ c2w, const float* __restrict__ c3w,
              const float* __restrict__ c4w, const float* __restrict__ c5w,
              const float* __restrict__ c1w, const float* __restrict__ pw,
              const float* __restrict__ linw)
{
    int i = blockIdx.x*256 + threadIdx.x;
    if (i >= WTS_TOT) return;
    float v;
    if (i < OFF_C3) {
        int p = i / 8192, rem = i - p*8192;
        int co = rem >> 6, ci = rem & 63;
        v = c2w[(co*64 + ci)*9 + p];
    } else if (i < OFF_C4) {
        int t = i - OFF_C3;
        int p = t / 16384, rem = t - p*16384;
        int co = rem >> 7, ci = rem & 127;
        v = c3w[(co*128 + ci)*9 + p];
    } else if (i < OFF_C5) {
        int t = i - OFF_C4;
        int p = t / 16384, rem = t - p*16384;
        int co = rem >> 7, ci = rem & 127;
        v = c4w[(co*128 + ci)*4 + p];
    } else if (i < OFF_C1)  v = c5w[i - OFF_C5];
    else if (i < OFF_PW)    v = c1w[i - OFF_C1];
    else if (i < OFF_LIN)   v = pw[i - OFF_PW];
    else                    v = linw[i - OFF_LIN];
    g_wts[i] = f2bits(v);
}

// ---------------------------------------------------------------------------
extern "C" void kernel_launch(void* const* d_in, const int* in_sizes, int n_in,
                              void* d_out, int out_size, void* d_ws, size_t ws_size,
                              hipStream_t stream)
{
    const float* x     = (const float*)d_in[0];
    const float* xyz   = (const float*)d_in[1];
    const float* c1_w  = (const float*)d_in[2];
    const float* c1_b  = (const float*)d_in[3];
    const float* c2_w  = (const float*)d_in[4];
    const float* c2_b  = (const float*)d_in[5];
    const float* c3_w  = (const float*)d_in[6];
    const float* c3_b  = (const float*)d_in[7];
    const float* c4_w  = (const float*)d_in[8];
    const float* c4_b  = (const float*)d_in[9];
    const float* c5_w  = (const float*)d_in[10];
    const float* c5_b  = (const float*)d_in[11];
    const float* rbn_s = (const float*)d_in[12];
    const float* rbn_b = (const float*)d_in[13];
    const float* p_w   = (const float*)d_in[14];
    const float* p_b   = (const float*)d_in[15];
    const float* pbn_s = (const float*)d_in[16];
    const float* pbn_b = (const float*)d_in[17];
    const float* lin_w = (const float*)d_in[18];
    const float* lin_b = (const float*)d_in[19];
    const float* w1_w  = (const float*)d_in[20];
    const float* w1_b  = (const float*)d_in[21];
    const float* w2_w  = (const float*)d_in[22];
    const float* w2_b  = (const float*)d_in[23];
    const float* w3_w  = (const float*)d_in[24];
    const float* w3_b  = (const float*)d_in[25];
    const float* wbn1_s = (const float*)d_in[26];
    const float* wbn1_b = (const float*)d_in[27];
    const float* wbn2_s = (const float*)d_in[28];
    const float* wbn2_b = (const float*)d_in[29];
    const float* wbn3_s = (const float*)d_in[30];
    const float* wbn3_b = (const float*)d_in[31];

    float* outB = (float*)d_out;                     // [2,128,32,512] fp32
    float* outA = outB + (size_t)B_*C_*HW2_;         // [2,128,64,1024] fp32

    u16 *wts, *b1, *b2, *b3, *yb;
    { void* p; hipGetSymbolAddress(&p, HIP_SYMBOL(g_wts)); wts = (u16*)p; }
    { void* p; hipGetSymbolAddress(&p, HIP_SYMBOL(g_b1));  b1  = (u16*)p; }
    { void* p; hipGetSymbolAddress(&p, HIP_SYMBOL(g_b2));  b2  = (u16*)p; }
    { void* p; hipGetSymbolAddress(&p, HIP_SYMBOL(g_b3));  b3  = (u16*)p; }
    { void* p; hipGetSymbolAddress(&p, HIP_SYMBOL(g_y));   yb  = (u16*)p; }
    u16* xb = yb;                                    // xb aliases g_y (dead by then)

    dim3 blk(256);

    k_wtrans<<<dim3((WTS_TOT + 255)/256), blk, 0, stream>>>(c2_w, c3_w, c4_w, c5_w,
                                                            c1_w, p_w, lin_w);
    k_xtrans<<<dim3(512, B_), blk, 0, stream>>>(x, xb);
    k_conv<64,3,1,1><<<dim3(512, B_), blk, 0, stream>>>(xb, wts+OFF_C2, c2_b,
                                                        rbn_s, rbn_b, b1);
    k_conv<128,3,2,2><<<dim3(512, B_), blk, 0, stream>>>(b1, wts+OFF_C3, c3_b,
                                                         rbn_s+128, rbn_b+128, b2);
    k_conv<128,2,2,1><<<dim3(512, B_), blk, 0, stream>>>(b2, wts+OFF_C4, c4_b,
                                                         rbn_s+256, rbn_b+256, b3);
    k_resA<<<dim3(512, B_), blk, 0, stream>>>(xb, b1, b2, b3, wts+OFF_C1, c1_b,
                                              wts+OFF_C5, c5_b, rbn_s+384, rbn_b+384, outA);
    k_pw3<<<dim3(512, B_), blk, 0, stream>>>(outA, wts+OFF_PW, p_b, pbn_s, pbn_b, b1);
    wn_kernel<<<dim3(1600, B_), blk, 0, stream>>>(xyz, w1_w, w1_b, w2_w, w2_b, w3_w, w3_b,
                                                  wbn1_s, wbn1_b, wbn2_s, wbn2_b,
                                                  wbn3_s, wbn3_b, b2);
    k_ycompute<<<dim3(512, B_), dim3(512), 0, stream>>>(b1, b2, yb);
    k_lin<<<dim3(128, B_), blk, 0, stream>>>(yb, wts+OFF_LIN, lin_b,
                                             pbn_s+384, pbn_b+384, outB);
}

// Round 3
// 610.711 us; speedup vs baseline: 1.3351x; 1.1097x over previous
//
#include <hip/hip_runtime.h>
#include <hip/hip_bf16.h>

typedef __hip_bfloat16 bf16;
typedef unsigned short u16;
typedef unsigned int   u32;

#define B_   2
#define CIN_ 64
#define C_   128
#define H_   64
#define W_   1024
#define HW_  (H_*W_)
#define H2_  32
#define W2_  512
#define HW2_ (H2_*W2_)

typedef __attribute__((ext_vector_type(8))) short bf16x8;
typedef __attribute__((ext_vector_type(4))) float f32x4;

// Transformed bf16 weights (row-major, k-contiguous per co row).
#define OFF_C2  0
#define OFF_C3  73728
#define OFF_C4  221184
#define OFF_C5  286720
#define OFF_C1  335872
#define OFF_PW  344064
#define OFF_LIN 393216
#define WTS_TOT 655360
__device__ __align__(16) u16 g_wts[WTS_TOT];
// Module-owned activation buffers (both batches live).
// b1/b2/b3 hold conv-pipeline activations in PX-MAJOR [hw][128] bf16 layout.
// (b1 later reused for h in [c][hw]; b2 later reused for wn.)
__device__ __align__(16) u16 g_b1[(size_t)B_*C_*HW_];      // 32 MiB
__device__ __align__(16) u16 g_b2[(size_t)B_*C_*HW_];      // 32 MiB
__device__ __align__(16) u16 g_b3[(size_t)B_*C_*HW_];      // 32 MiB
__device__ __align__(16) u16 g_xb[(size_t)B_*HW_*CIN_];    // 16 MiB (xb [hw][64])

__device__ __forceinline__ float bits2f(u16 u){
    u32 x = ((u32)u) << 16; float f; __builtin_memcpy(&f, &x, 4); return f;
}
__device__ __forceinline__ u16 f2bits(float v){
    bf16 h = __float2bfloat16(v); u16 u; __builtin_memcpy(&u, &h, 2); return u;
}
__device__ __forceinline__ float lrelu(float v){ return v > 0.f ? v : 0.01f*v; }
__device__ __forceinline__ float relu (float v){ return v > 0.f ? v : 0.f; }

// ---------------------------------------------------------------------------
// MFMA tile machinery. Tile M=128 (co) x N=128 (pix), K-step 32.
// A/B LDS rows stride LSTR=40 u16 (+16B pad, odd 16B-granule count).
// ---------------------------------------------------------------------------
#define LSTR 40
#define PSTR 136   // full-K (128) B stride for k_pw3 / k_yfused
#define TSTR 136   // epilogue transpose tile stride (16B-aligned rows)

__device__ __forceinline__ void stage_A(u16* As, const u16* w, int wstr, int col0, int tid)
{
#pragma unroll
    for (int r = 0; r < 2; r++) {
        int e = tid + 256*r;
        int co = e >> 2, ch = e & 3;
        *(uint4*)&As[co*LSTR + ch*8] = *(const uint4*)&w[co*wstr + col0 + ch*8];
    }
}

// B-tile staging from px-major activations: row j = pixel, k = channels
// (k-contiguous in memory -> pure vector copy, no transpose).
__device__ __forceinline__ void stage_B_pm(u16* Bs, const u16* src, int rowStride,
                                           int kc, int tid)
{
#pragma unroll
    for (int r = 0; r < 2; r++) {
        int e = tid + 256*r;
        int j = e >> 2, g = e & 3;
        *(uint4*)&Bs[j*LSTR + g*8] =
            *(const uint4*)&src[(size_t)j*rowStride + kc*32 + g*8];
    }
}

__device__ __forceinline__ void mfma_step_s(const u16* As, const u16* Bs, int bstr, int koff,
                                            int lane, int wm, int wn_, f32x4 acc[4][4])
{
    const int quad = lane >> 4, l15 = lane & 15;
    bf16x8 a[4], b[4];
#pragma unroll
    for (int i = 0; i < 4; i++)
        a[i] = *(const bf16x8*)&As[(wm*64 + i*16 + l15)*LSTR + quad*8];
#pragma unroll
    for (int j = 0; j < 4; j++)
        b[j] = *(const bf16x8*)&Bs[(wn_*64 + j*16 + l15)*bstr + koff + quad*8];
#pragma unroll
    for (int i = 0; i < 4; i++)
#pragma unroll
        for (int j = 0; j < 4; j++)
            acc[i][j] = __builtin_amdgcn_mfma_f32_16x16x32_bf16(a[i], b[j], acc[i][j], 0, 0, 0);
}

__device__ __forceinline__ void mfma_step(const u16* As, const u16* Bs,
                                          int lane, int wm, int wn_, f32x4 acc[4][4])
{
    mfma_step_s(As, Bs, LSTR, 0, lane, wm, wn_, acc);
}

__device__ __forceinline__ void init_bias(f32x4 acc[4][4], const float* bias, int wm, int lane)
{
    const int quad = lane >> 4;
#pragma unroll
    for (int i = 0; i < 4; i++)
#pragma unroll
        for (int r = 0; r < 4; r++) {
            float bv = bias[wm*64 + i*16 + quad*4 + r];
#pragma unroll
            for (int j = 0; j < 4; j++) acc[i][j][r] = bv;
        }
}

// ---------------------------------------------------------------------------
// x transpose: fp32 [64][HW] -> bf16 [HW][64] (enables vector B-staging in
// c2 conv and resA shortcut). grid (512, B_), block 256.
// ---------------------------------------------------------------------------
#define XTS 70
__global__ __launch_bounds__(256)
void k_xtrans(const float* __restrict__ x0, u16* __restrict__ xb0)
{
    __shared__ __align__(16) u16 T[128*XTS];
    const int tid = threadIdx.x;
    const float* x = x0 + (size_t)blockIdx.y*CIN_*HW_;
    u16* xb = xb0 + (size_t)blockIdx.y*HW_*CIN_;
    const int pix0 = blockIdx.x * 128;
#pragma unroll
    for (int r = 0; r < 8; r++) {
        int e = tid + 256*r;               // 2048 items: 64 c x 32 px-groups
        int c = e >> 5, p4 = (e & 31)*4;
        float4 v = *(const float4*)&x[(size_t)c*HW_ + pix0 + p4];
        T[(p4+0)*XTS + c] = f2bits(v.x);
        T[(p4+1)*XTS + c] = f2bits(v.y);
        T[(p4+2)*XTS + c] = f2bits(v.z);
        T[(p4+3)*XTS + c] = f2bits(v.w);
    }
    __syncthreads();
#pragma unroll
    for (int r = 0; r < 4; r++) {
        int e = tid + 256*r;               // 1024 granules: 128 px x 8
        int p = e >> 3, g = e & 7;
        // rows are XTS*2=140B apart; granule addr 8B-aligned -> copy as 2 uint2
        const u16* s = &T[p*XTS + g*8];
        u16* d = &xb[(size_t)(pix0+p)*CIN_ + g*8];
        *(uint2*)&d[0] = *(const uint2*)&s[0];
        *(uint2*)&d[4] = *(const uint2*)&s[4];
    }
}

// ---------------------------------------------------------------------------
// Conv as shift-decomposed GEMM over px-major activations.
// grid (512, B_), block 256.  in: [hw][CI] bf16, out: [hw][128] bf16.
// ---------------------------------------------------------------------------
template<int CI, int KS, int DIL, int PAD>
__global__ __launch_bounds__(256)
void k_conv(const u16* __restrict__ in0, const u16* __restrict__ wT,
            const float* __restrict__ bias, const float* __restrict__ bns,
            const float* __restrict__ bnb, u16* __restrict__ out0)
{
    __shared__ __align__(16) u16 S[128*TSTR];     // 34.8 KB; As|Bs, reused as T
    u16* As = S;
    u16* Bs = S + 128*LSTR;
    const int tid = threadIdx.x, lane = tid & 63, wave = tid >> 6;
    const int wm = wave & 1, wn_ = wave >> 1;
    const u16* in = in0 + (size_t)blockIdx.y*HW_*CI;
    u16* out = out0 + (size_t)blockIdx.y*HW_*C_;
    const int pix0 = blockIdx.x * 128;
    const int y = pix0 >> 10, x0 = pix0 & 1023;

    f32x4 acc[4][4];
    init_bias(acc, bias, wm, lane);

    for (int p = 0; p < KS*KS; p++) {
        int dy = (p/KS)*DIL - PAD, dx = (p%KS)*DIL - PAD;
        int yy = y + dy;
        if (yy < 0 || yy >= H_) continue;          // wave-uniform (tile = one row)
        const u16* srow = in + (size_t)yy*W_*CI;
        for (int kc = 0; kc < CI/32; kc++) {
            stage_A(As, wT + p*128*CI, CI, kc*32, tid);
#pragma unroll
            for (int r = 0; r < 2; r++) {
                int e = tid + 256*r;
                int j = e >> 2, g = e & 3;
                int xx = x0 + dx + j;
                uint4 v = make_uint4(0u, 0u, 0u, 0u);
                if ((unsigned)xx < (unsigned)W_)
                    v = *(const uint4*)&srow[(size_t)xx*CI + kc*32 + g*8];
                *(uint4*)&Bs[j*LSTR + g*8] = v;
            }
            __syncthreads();
            mfma_step(As, Bs, lane, wm, wn_, acc);
            __syncthreads();
        }
    }
    // Epilogue: bn+lrelu -> LDS transpose tile [px][co] -> vector px-major store
    const int quad = lane >> 4, l15 = lane & 15;
    u16* T = S;
#pragma unroll
    for (int i = 0; i < 4; i++)
#pragma unroll
        for (int r = 0; r < 4; r++) {
            int co = wm*64 + i*16 + quad*4 + r;
            float ss = bns[co], tt = bnb[co];
#pragma unroll
            for (int j = 0; j < 4; j++) {
                float v = lrelu(acc[i][j][r]) * ss + tt;
                T[(wn_*64 + j*16 + l15)*TSTR + co] = f2bits(v);
            }
        }
    __syncthreads();
#pragma unroll
    for (int r = 0; r < 8; r++) {
        int e = tid + 256*r;
        int px = e >> 4, g = e & 15;
        *(uint4*)&out[(size_t)(pix0+px)*C_ + g*8] = *(const uint4*)&T[px*TSTR + g*8];
    }
}

// ---------------------------------------------------------------------------
// resA = bn3(lrelu(c5_w@[A1;A2;A3] + c5_b)) + lrelu(c1_w@x + c1_b)  (fp32 out)
// Inputs xb/A1/A2/A3 in px-major layout; output stays [C][HW] fp32 (required).
// ---------------------------------------------------------------------------
__global__ __launch_bounds__(256)
void k_resA(const u16* __restrict__ xb0, const u16* __restrict__ a10,
            const u16* __restrict__ a20, const u16* __restrict__ a30,
            const u16* __restrict__ wc1, const float* __restrict__ c1b,
            const u16* __restrict__ wc5, const float* __restrict__ c5b,
            const float* __restrict__ s3, const float* __restrict__ b3,
            float* __restrict__ out0)
{
    __shared__ __align__(16) u16 As[128*LSTR];
    __shared__ __align__(16) u16 Bs[128*LSTR];
    const int tid = threadIdx.x, lane = tid & 63, wave = tid >> 6;
    const int wm = wave & 1, wn_ = wave >> 1;
    const int b = blockIdx.y;
    const u16* xb = xb0 + (size_t)b*HW_*CIN_;
    const u16* aa[3] = { a10 + (size_t)b*HW_*C_, a20 + (size_t)b*HW_*C_, a30 + (size_t)b*HW_*C_ };
    float* out = out0 + (size_t)b*C_*HW_;
    const int pix0 = blockIdx.x * 128;
    const int quad = lane >> 4, l15 = lane & 15;

    // shortcut: K=64 over xb
    f32x4 acc[4][4];
    init_bias(acc, c1b, wm, lane);
    for (int kc = 0; kc < 2; kc++) {
        stage_A(As, wc1, 64, kc*32, tid);
        stage_B_pm(Bs, xb + (size_t)pix0*CIN_, CIN_, kc, tid);
        __syncthreads();
        mfma_step(As, Bs, lane, wm, wn_, acc);
        __syncthreads();
    }
    float sc[4][4][4];
#pragma unroll
    for (int i = 0; i < 4; i++)
#pragma unroll
        for (int j = 0; j < 4; j++)
#pragma unroll
            for (int r = 0; r < 4; r++) sc[i][j][r] = lrelu(acc[i][j][r]);

    // main: K=384 over [A1;A2;A3]
    init_bias(acc, c5b, wm, lane);
    for (int s = 0; s < 3; s++) {
        const u16* src = aa[s] + (size_t)pix0*C_;
        for (int kc = 0; kc < 4; kc++) {
            stage_A(As, wc5, 384, s*128 + kc*32, tid);
            stage_B_pm(Bs, src, C_, kc, tid);
            __syncthreads();
            mfma_step(As, Bs, lane, wm, wn_, acc);
            __syncthreads();
        }
    }
#pragma unroll
    for (int i = 0; i < 4; i++)
#pragma unroll
        for (int r = 0; r < 4; r++) {
            int co = wm*64 + i*16 + quad*4 + r;
            float ss = s3[co], tt = b3[co];
#pragma unroll
            for (int j = 0; j < 4; j++) {
                float v = lrelu(acc[i][j][r]) * ss + tt + sc[i][j][r];
                out[co*HW_ + pix0 + wn_*64 + j*16 + l15] = v;
            }
        }
}

// ---------------------------------------------------------------------------
// Fused 3-layer pointwise MLP: h = relu(bn(W3 relu(bn(W2 relu(bn(W1 resA)))))).
// One block owns 128 pixels end-to-end; inter-layer activations in LDS.
// Output h stays channel-major [C][HW] (k_yfused wants x-contiguous rows).
// ---------------------------------------------------------------------------
__global__ __launch_bounds__(256)
void k_pw3(const float* __restrict__ in0, const u16* __restrict__ w,
           const float* __restrict__ pb, const float* __restrict__ ps,
           const float* __restrict__ pbb, u16* __restrict__ out0)
{
    __shared__ __align__(16) u16 As[128*LSTR];
    __shared__ __align__(16) u16 B0[128*PSTR];
    __shared__ __align__(16) u16 B1[128*PSTR];
    const int tid = threadIdx.x, lane = tid & 63, wave = tid >> 6;
    const int wm = wave & 1, wn_ = wave >> 1;
    const int b = blockIdx.y;
    const float* in = in0 + (size_t)b*C_*HW_;
    u16* out = out0 + (size_t)b*C_*HW_;
    const int pix0 = blockIdx.x * 128;
    const int quad = lane >> 4, l15 = lane & 15;

    // Stage B0 [pix][k] from fp32 resA (vector loads along pix, scatter to LDS)
    for (int e = tid; e < 128*32; e += 256) {
        int kk = e >> 5, j4 = (e & 31)*4;
        float4 v = *(const float4*)&in[kk*HW_ + pix0 + j4];
        u16* d = &B0[j4*PSTR + kk];
        d[0]      = f2bits(v.x);
        d[PSTR]   = f2bits(v.y);
        d[2*PSTR] = f2bits(v.z);
        d[3*PSTR] = f2bits(v.w);
    }

    u16* Bc = B0;
    u16* Bn = B1;
#pragma unroll
    for (int L = 0; L < 3; L++) {
        f32x4 acc[4][4];
        init_bias(acc, pb + L*128, wm, lane);
        for (int kc = 0; kc < 4; kc++) {
            stage_A(As, w + L*16384, 128, kc*32, tid);
            __syncthreads();                       // As + (Bc writes) visible
            mfma_step_s(As, Bc, PSTR, kc*32, lane, wm, wn_, acc);
            __syncthreads();                       // done reading As
        }
        const float* ss = ps + L*128;
        const float* tt = pbb + L*128;
        if (L < 2) {
#pragma unroll
            for (int i = 0; i < 4; i++)
#pragma unroll
                for (int r = 0; r < 4; r++) {
                    int co = wm*64 + i*16 + quad*4 + r;
                    float s1 = ss[co], t1 = tt[co];
#pragma unroll
                    for (int j = 0; j < 4; j++) {
                        float v = relu(acc[i][j][r] * s1 + t1);
                        Bn[(wn_*64 + j*16 + l15)*PSTR + co] = f2bits(v);
                    }
                }
            u16* t = Bc; Bc = Bn; Bn = t;
        } else {
#pragma unroll
            for (int i = 0; i < 4; i++)
#pragma unroll
                for (int r = 0; r < 4; r++) {
                    int co = wm*64 + i*16 + quad*4 + r;
                    float s1 = ss[co], t1 = tt[co];
#pragma unroll
                    for (int j = 0; j < 4; j++) {
                        float v = relu(acc[i][j][r] * s1 + t1);
                        out[co*HW_ + pix0 + wn_*64 + j*16 + l15] = f2bits(v);
                    }
                }
        }
    }
}

// ---------------------------------------------------------------------------
// WeightNet: xyz fp32 -> bf16 [16,25,H2,W2] per batch.
// ---------------------------------------------------------------------------
__global__ __launch_bounds__(256)
void wn_kernel(const float* __restrict__ xyz0,
               const float* __restrict__ w1w, const float* __restrict__ w1b,
               const float* __restrict__ w2w, const float* __restrict__ w2b,
               const float* __restrict__ w3w, const float* __restrict__ w3b,
               const float* __restrict__ s1, const float* __restrict__ bb1,
               const float* __restrict__ s2, const float* __restrict__ bb2,
               const float* __restrict__ s3, const float* __restrict__ bb3,
               u16* __restrict__ out0)
{
    const float* xyz = xyz0 + (size_t)blockIdx.y*3*HW_;
    u16* out = out0 + (size_t)blockIdx.y*400*HW2_;
    int idx = blockIdx.x*256 + threadIdx.x;
    int j = idx & (W2_-1); int t = idx >> 9;
    int i = t & (H2_-1);   int k = t >> 5;
    int kh = k / 5, kw = k - kh*5;
    int yy = 2*i + kh - 2, xx = 2*j + kw - 2;
    bool inr = (yy >= 0 && yy < H_ && xx >= 0 && xx < W_);

    float g[3];
#pragma unroll
    for (int c = 0; c < 3; c++) {
        float ctr = xyz[c*HW_ + (2*i)*W_ + 2*j];
        float v = inr ? xyz[c*HW_ + yy*W_ + xx] : 0.f;
        g[c] = v - ctr;
    }
    float a1[8];
#pragma unroll
    for (int n = 0; n < 8; n++) {
        float v = w1b[n];
#pragma unroll
        for (int c = 0; c < 3; c++) v += w1w[n*3 + c] * g[c];
        a1[n] = relu(v * s1[n] + bb1[n]);
    }
    float a2[8];
#pragma unroll
    for (int n = 0; n < 8; n++) {
        float v = w2b[n];
#pragma unroll
        for (int m = 0; m < 8; m++) v += w2w[n*8 + m] * a1[m];
        a2[n] = relu(v * s2[n] + bb2[n]);
    }
#pragma unroll
    for (int n = 0; n < 16; n++) {
        float v = w3b[n];
#pragma unroll
        for (int m = 0; m < 8; m++) v += w3w[n*8 + m] * a2[m];
        v = relu(v * s3[n] + bb3[n]);
        out[(n*25 + k)*HW2_ + i*W2_ + j] = f2bits(v);
    }
}

// ---------------------------------------------------------------------------
// Fused ycompute + linear head:
//   y[px][c*16+n] = sum_k unf(h)[c][k][px] * wn[n][k][px]     (bf16, LDS only)
//   resB[co][px]  = relu(bn(sum_{c,n} lin_w[co][c*16+n] * y[px][c*16+n] + b))
// grid (32 i2 * 8 jt, B_), block 512.  Per c0-chunk (8 ch): y sub-tile
// [64 px][128 k] in LDS -> 4 MFMA K-steps vs lin_w K-slice.  16 chunks = K=2048.
// Phase-1 lanes: (n = tid&15 fast, pxq = tid>>4) -> 16-way broadcast slab reads.
// ---------------------------------------------------------------------------
__global__ __launch_bounds__(512, 4)
void k_yfused(const u16* __restrict__ h0, const u16* __restrict__ wn0,
              const u16* __restrict__ w, const float* __restrict__ bias,
              const float* __restrict__ bns, const float* __restrict__ bnb,
              float* __restrict__ out0)
{
    __shared__ __align__(16) float slab[40*148];   // 23.7 KB (8 cc * 5 rr rows)
    __shared__ __align__(16) u16 As[128*PSTR];     // 34.8 KB (lin_w K-slice 128)
    __shared__ __align__(16) u16 Bs[64*PSTR];      // 17.4 KB (y sub-tile)
    const int tid = threadIdx.x;
    const int bx = blockIdx.x;
    const int j0 = (bx & 7) * 64;
    const int i2 = bx >> 3;
    const int b  = blockIdx.y;
    const u16* h  = h0  + (size_t)b*C_*HW_;
    const u16* wn = wn0 + (size_t)b*400*HW2_;
    float* out = out0 + (size_t)b*C_*HW2_;

    // phase-1 roles: n fast (broadcast group), pxq = px-pair index
    const int n = tid & 15, pxq = tid >> 4;        // pxq 0..31
    // phase-2 roles
    const int lane = tid & 63, wave = tid >> 6;
    const int wm4 = wave & 3, wnp = wave >> 2;     // 4x32 co, 2x32 px
    const int quad = lane >> 4, l15 = lane & 15;

    // wn for this thread's (n, px-pair): 25 taps f32 in regs (50 VGPR)
    float wnreg[25][2];
    {
        const u16* wb = wn + (n*25)*HW2_ + i2*W2_ + j0 + pxq*2;
#pragma unroll
        for (int k = 0; k < 25; k++) {
            u32 t = *(const u32*)(wb + k*HW2_);
            wnreg[k][0] = bits2f((u16)(t & 0xffff));
            wnreg[k][1] = bits2f((u16)(t >> 16));
        }
    }

    f32x4 acc[2][2];
#pragma unroll
    for (int i = 0; i < 2; i++)
#pragma unroll
        for (int r = 0; r < 4; r++) {
            float bv = bias[wm4*32 + i*16 + quad*4 + r];
            acc[i][0][r] = bv;
            acc[i][1][r] = bv;
        }

    for (int c0 = 0; c0 < 128; c0 += 8) {
        __syncthreads();                           // prev mfma + y-compute done
        // Fill slab: 8 cc x 5 rr x 18 uint4-groups (identical math to before)
        for (int e = tid; e < 720; e += 512) {
            int cc = e / 90, rem = e - cc*90;
            int rr = rem / 18, g = rem - rr*18;
            int yy = 2*i2 + rr - 2;
            int xs0 = 2*j0 - 8 + 8*g;              // 16B-aligned global offset
            float f[8];
            if ((unsigned)yy < (unsigned)H_ && (unsigned)xs0 <= (unsigned)(W_-8)) {
                uint4 v = *(const uint4*)&h[(c0+cc)*HW_ + yy*W_ + xs0];
                f[0] = bits2f((u16)(v.x & 0xffff)); f[1] = bits2f((u16)(v.x >> 16));
                f[2] = bits2f((u16)(v.y & 0xffff)); f[3] = bits2f((u16)(v.y >> 16));
                f[4] = bits2f((u16)(v.z & 0xffff)); f[5] = bits2f((u16)(v.z >> 16));
                f[6] = bits2f((u16)(v.w & 0xffff)); f[7] = bits2f((u16)(v.w >> 16));
            } else if ((unsigned)yy < (unsigned)H_) {
#pragma unroll
                for (int m = 0; m < 8; m++) {
                    int xs = xs0 + m;
                    f[m] = ((unsigned)xs < (unsigned)W_)
                         ? bits2f(h[(c0+cc)*HW_ + yy*W_ + xs]) : 0.f;
                }
            } else {
#pragma unroll
                for (int m = 0; m < 8; m++) f[m] = 0.f;
            }
            float* d = &slab[(cc*5 + rr)*148 + 2 + 8*g];
            *(float2*)(d+0) = make_float2(f[0], f[1]);
            *(float2*)(d+2) = make_float2(f[2], f[3]);
            *(float2*)(d+4) = make_float2(f[4], f[5]);
            *(float2*)(d+6) = make_float2(f[6], f[7]);
        }
        // Stage lin_w K-slice [128 co][128 k] (cols c0*16 .. +128)
#pragma unroll
        for (int r = 0; r < 4; r++) {
            int e = tid + 512*r;                   // 2048 granules
            int co = e >> 4, g = e & 15;
            *(uint4*)&As[co*PSTR + g*8] = *(const uint4*)&w[co*2048 + c0*16 + g*8];
        }
        __syncthreads();                           // slab + As ready
        // y-compute into Bs [px][cc*16+n]
#pragma unroll 2
        for (int cc = 0; cc < 8; cc++) {
            float yv0 = 0.f, yv1 = 0.f;
#pragma unroll
            for (int rr = 0; rr < 5; rr++) {
                const float* fr = &slab[(cc*5 + rr)*148 + 8 + 4*pxq];
                float4 A  = *(const float4*)fr;
                float4 Bv = *(const float4*)(fr + 4);
                yv0 += A.x*wnreg[rr*5+0][0] + A.y*wnreg[rr*5+1][0]
                     + A.z*wnreg[rr*5+2][0] + A.w*wnreg[rr*5+3][0]
                     + Bv.x*wnreg[rr*5+4][0];
                yv1 += A.z*wnreg[rr*5+0][1] + A.w*wnreg[rr*5+1][1]
                     + Bv.x*wnreg[rr*5+2][1] + Bv.y*wnreg[rr*5+3][1]
                     + Bv.z*wnreg[rr*5+4][1];
            }
            Bs[(2*pxq)  *PSTR + cc*16 + n] = f2bits(yv0);
            Bs[(2*pxq+1)*PSTR + cc*16 + n] = f2bits(yv1);
        }
        __syncthreads();                           // Bs ready
#pragma unroll
        for (int kc = 0; kc < 4; kc++) {
            bf16x8 a0 = *(const bf16x8*)&As[(wm4*32 +  0 + l15)*PSTR + kc*32 + quad*8];
            bf16x8 a1 = *(const bf16x8*)&As[(wm4*32 + 16 + l15)*PSTR + kc*32 + quad*8];
            bf16x8 b0 = *(const bf16x8*)&Bs[(wnp*32 +  0 + l15)*PSTR + kc*32 + quad*8];
            bf16x8 b1 = *(const bf16x8*)&Bs[(wnp*32 + 16 + l15)*PSTR + kc*32 + quad*8];
            acc[0][0] = __builtin_amdgcn_mfma_f32_16x16x32_bf16(a0, b0, acc[0][0], 0, 0, 0);
            acc[0][1] = __builtin_amdgcn_mfma_f32_16x16x32_bf16(a0, b1, acc[0][1], 0, 0, 0);
            acc[1][0] = __builtin_amdgcn_mfma_f32_16x16x32_bf16(a1, b0, acc[1][0], 0, 0, 0);
            acc[1][1] = __builtin_amdgcn_mfma_f32_16x16x32_bf16(a1, b1, acc[1][1], 0, 0, 0);
        }
    }
    // epilogue: bn + relu -> fp32 resB
#pragma unroll
    for (int i = 0; i < 2; i++)
#pragma unroll
        for (int r = 0; r < 4; r++) {
            int co = wm4*32 + i*16 + quad*4 + r;
            float ss = bns[co], tt = bnb[co];
#pragma unroll
            for (int j = 0; j < 2; j++) {
                float v = relu(acc[i][j][r] * ss + tt);
                out[co*HW2_ + i2*W2_ + j0 + wnp*32 + j*16 + l15] = v;
            }
        }
}

// ---------------------------------------------------------------------------
// Weight transform: fp32 -> bf16 g_wts (k-contiguous layouts).
// ---------------------------------------------------------------------------
__global__ __launch_bounds__(256)
void k_wtrans(const float* __restrict__ c2w, const float* __restrict__ c3w,
              const float* __restrict__ c4w, const float* __restrict__ c5w,
              const float* __restrict__ c1w, const float* __restrict__ pw,
              const float* __restrict__ linw)
{
    int i = blockIdx.x*256 + threadIdx.x;
    if (i >= WTS_TOT) return;
    float v;
    if (i < OFF_C3) {
        int p = i / 8192, rem = i - p*8192;
        int co = rem >> 6, ci = rem & 63;
        v = c2w[(co*64 + ci)*9 + p];
    } else if (i < OFF_C4) {
        int t = i - OFF_C3;
        int p = t / 16384, rem = t - p*16384;
        int co = rem >> 7, ci = rem & 127;
        v = c3w[(co*128 + ci)*9 + p];
    } else if (i < OFF_C5) {
        int t = i - OFF_C4;
        int p = t / 16384, rem = t - p*16384;
        int co = rem >> 7, ci = rem & 127;
        v = c4w[(co*128 + ci)*4 + p];
    } else if (i < OFF_C1)  v = c5w[i - OFF_C5];
    else if (i < OFF_PW)    v = c1w[i - OFF_C1];
    else if (i < OFF_LIN)   v = pw[i - OFF_PW];
    else                    v = linw[i - OFF_LIN];
    g_wts[i] = f2bits(v);
}

// ---------------------------------------------------------------------------
extern "C" void kernel_launch(void* const* d_in, const int* in_sizes, int n_in,
                              void* d_out, int out_size, void* d_ws, size_t ws_size,
                              hipStream_t stream)
{
    const float* x     = (const float*)d_in[0];
    const float* xyz   = (const float*)d_in[1];
    const float* c1_w  = (const float*)d_in[2];
    const float* c1_b  = (const float*)d_in[3];
    const float* c2_w  = (const float*)d_in[4];
    const float* c2_b  = (const float*)d_in[5];
    const float* c3_w  = (const float*)d_in[6];
    const float* c3_b  = (const float*)d_in[7];
    const float* c4_w  = (const float*)d_in[8];
    const float* c4_b  = (const float*)d_in[9];
    const float* c5_w  = (const float*)d_in[10];
    const float* c5_b  = (const float*)d_in[11];
    const float* rbn_s = (const float*)d_in[12];
    const float* rbn_b = (const float*)d_in[13];
    const float* p_w   = (const float*)d_in[14];
    const float* p_b   = (const float*)d_in[15];
    const float* pbn_s = (const float*)d_in[16];
    const float* pbn_b = (const float*)d_in[17];
    const float* lin_w = (const float*)d_in[18];
    const float* lin_b = (const float*)d_in[19];
    const float* w1_w  = (const float*)d_in[20];
    const float* w1_b  = (const float*)d_in[21];
    const float* w2_w  = (const float*)d_in[22];
    const float* w2_b  = (const float*)d_in[23];
    const float* w3_w  = (const float*)d_in[24];
    const float* w3_b  = (const float*)d_in[25];
    const float* wbn1_s = (const float*)d_in[26];
    const float* wbn1_b = (const float*)d_in[27];
    const float* wbn2_s = (const float*)d_in[28];
    const float* wbn2_b = (const float*)d_in[29];
    const float* wbn3_s = (const float*)d_in[30];
    const float* wbn3_b = (const float*)d_in[31];

    float* outB = (float*)d_out;                     // [2,128,32,512] fp32
    float* outA = outB + (size_t)B_*C_*HW2_;         // [2,128,64,1024] fp32

    u16 *wts, *b1, *b2, *b3, *xb;
    { void* p; hipGetSymbolAddress(&p, HIP_SYMBOL(g_wts)); wts = (u16*)p; }
    { void* p; hipGetSymbolAddress(&p, HIP_SYMBOL(g_b1));  b1  = (u16*)p; }
    { void* p; hipGetSymbolAddress(&p, HIP_SYMBOL(g_b2));  b2  = (u16*)p; }
    { void* p; hipGetSymbolAddress(&p, HIP_SYMBOL(g_b3));  b3  = (u16*)p; }
    { void* p; hipGetSymbolAddress(&p, HIP_SYMBOL(g_xb));  xb  = (u16*)p; }

    dim3 blk(256);

    k_wtrans<<<dim3((WTS_TOT + 255)/256), blk, 0, stream>>>(c2_w, c3_w, c4_w, c5_w,
                                                            c1_w, p_w, lin_w);
    k_xtrans<<<dim3(512, B_), blk, 0, stream>>>(x, xb);
    k_conv<64,3,1,1><<<dim3(512, B_), blk, 0, stream>>>(xb, wts+OFF_C2, c2_b,
                                                        rbn_s, rbn_b, b1);
    k_conv<128,3,2,2><<<dim3(512, B_), blk, 0, stream>>>(b1, wts+OFF_C3, c3_b,
                                                         rbn_s+128, rbn_b+128, b2);
    k_conv<128,2,2,1><<<dim3(512, B_), blk, 0, stream>>>(b2, wts+OFF_C4, c4_b,
                                                         rbn_s+256, rbn_b+256, b3);
    k_resA<<<dim3(512, B_), blk, 0, stream>>>(xb, b1, b2, b3, wts+OFF_C1, c1_b,
                                              wts+OFF_C5, c5_b, rbn_s+384, rbn_b+384, outA);
    k_pw3<<<dim3(512, B_), blk, 0, stream>>>(outA, wts+OFF_PW, p_b, pbn_s, pbn_b, b1);
    wn_kernel<<<dim3(1600, B_), blk, 0, stream>>>(xyz, w1_w, w1_b, w2_w, w2_b, w3_w, w3_b,
                                                  wbn1_s, wbn1_b, wbn2_s, wbn2_b,
                                                  wbn3_s, wbn3_b, b2);
    k_yfused<<<dim3(256, B_), dim3(512), 0, stream>>>(b1, b2, wts+OFF_LIN, lin_b,
                                                      pbn_s+384, pbn_b+384, outB);
}

// Round 4
// 570.613 us; speedup vs baseline: 1.4289x; 1.0703x over previous
//
#include <hip/hip_runtime.h>
#include <hip/hip_bf16.h>

typedef __hip_bfloat16 bf16;
typedef unsigned short u16;
typedef unsigned int   u32;

#define B_   2
#define CIN_ 64
#define C_   128
#define H_   64
#define W_   1024
#define HW_  (H_*W_)
#define H2_  32
#define W2_  512
#define HW2_ (H2_*W2_)

typedef __attribute__((ext_vector_type(8))) short bf16x8;
typedef __attribute__((ext_vector_type(4))) float f32x4;

// Transformed bf16 weights (row-major, k-contiguous per co row).
#define OFF_C2  0
#define OFF_C3  73728
#define OFF_C4  221184
#define OFF_C5  286720
#define OFF_C1  335872
#define OFF_PW  344064
#define OFF_LIN 393216
#define WTS_TOT 655360
__device__ __align__(16) u16 g_wts[WTS_TOT];
// Module-owned activation buffers (both batches live).
// b1/b2/b3 hold conv-pipeline activations in PX-MAJOR [hw][128] bf16 layout.
// (b1 later reused for h in [c][hw]; b2 later reused for wn.)
__device__ __align__(16) u16 g_b1[(size_t)B_*C_*HW_];      // 32 MiB
__device__ __align__(16) u16 g_b2[(size_t)B_*C_*HW_];      // 32 MiB
__device__ __align__(16) u16 g_b3[(size_t)B_*C_*HW_];      // 32 MiB
__device__ __align__(16) u16 g_xb[(size_t)B_*HW_*CIN_];    // 16 MiB (xb [hw][64])

__device__ __forceinline__ float bits2f(u16 u){
    u32 x = ((u32)u) << 16; float f; __builtin_memcpy(&f, &x, 4); return f;
}
__device__ __forceinline__ u16 f2bits(float v){
    bf16 h = __float2bfloat16(v); u16 u; __builtin_memcpy(&u, &h, 2); return u;
}
__device__ __forceinline__ float lrelu(float v){ return v > 0.f ? v : 0.01f*v; }
__device__ __forceinline__ float relu (float v){ return v > 0.f ? v : 0.f; }

// ---------------------------------------------------------------------------
// MFMA tile machinery. Tile M=128 (co) x N=128 (pix), K-step 32.
// A/B LDS rows stride LSTR=40 u16 (+16B pad, odd 16B-granule count).
// ---------------------------------------------------------------------------
#define LSTR 40
#define PSTR 136   // full-K (128) B stride for k_pw3 / k_yfused
#define TSTR 136   // epilogue transpose tile stride (16B-aligned rows)

__device__ __forceinline__ void stage_A(u16* As, const u16* w, int wstr, int col0, int tid)
{
#pragma unroll
    for (int r = 0; r < 2; r++) {
        int e = tid + 256*r;
        int co = e >> 2, ch = e & 3;
        *(uint4*)&As[co*LSTR + ch*8] = *(const uint4*)&w[co*wstr + col0 + ch*8];
    }
}

// B-tile staging from px-major activations: row j = pixel, k = channels
// (k-contiguous in memory -> pure vector copy, no transpose).
__device__ __forceinline__ void stage_B_pm(u16* Bs, const u16* src, int rowStride,
                                           int kc, int tid)
{
#pragma unroll
    for (int r = 0; r < 2; r++) {
        int e = tid + 256*r;
        int j = e >> 2, g = e & 3;
        *(uint4*)&Bs[j*LSTR + g*8] =
            *(const uint4*)&src[(size_t)j*rowStride + kc*32 + g*8];
    }
}

__device__ __forceinline__ void mfma_step_s(const u16* As, const u16* Bs, int bstr, int koff,
                                            int lane, int wm, int wn_, f32x4 acc[4][4])
{
    const int quad = lane >> 4, l15 = lane & 15;
    bf16x8 a[4], b[4];
#pragma unroll
    for (int i = 0; i < 4; i++)
        a[i] = *(const bf16x8*)&As[(wm*64 + i*16 + l15)*LSTR + quad*8];
#pragma unroll
    for (int j = 0; j < 4; j++)
        b[j] = *(const bf16x8*)&Bs[(wn_*64 + j*16 + l15)*bstr + koff + quad*8];
#pragma unroll
    for (int i = 0; i < 4; i++)
#pragma unroll
        for (int j = 0; j < 4; j++)
            acc[i][j] = __builtin_amdgcn_mfma_f32_16x16x32_bf16(a[i], b[j], acc[i][j], 0, 0, 0);
}

__device__ __forceinline__ void mfma_step(const u16* As, const u16* Bs,
                                          int lane, int wm, int wn_, f32x4 acc[4][4])
{
    mfma_step_s(As, Bs, LSTR, 0, lane, wm, wn_, acc);
}

__device__ __forceinline__ void init_bias(f32x4 acc[4][4], const float* bias, int wm, int lane)
{
    const int quad = lane >> 4;
#pragma unroll
    for (int i = 0; i < 4; i++)
#pragma unroll
        for (int r = 0; r < 4; r++) {
            float bv = bias[wm*64 + i*16 + quad*4 + r];
#pragma unroll
            for (int j = 0; j < 4; j++) acc[i][j][r] = bv;
        }
}

// ---------------------------------------------------------------------------
// x transpose: fp32 [64][HW] -> bf16 [HW][64] (enables vector B-staging in
// c2 conv and resA shortcut). grid (512, B_), block 256.
// ---------------------------------------------------------------------------
#define XTS 70
__global__ __launch_bounds__(256)
void k_xtrans(const float* __restrict__ x0, u16* __restrict__ xb0)
{
    __shared__ __align__(16) u16 T[128*XTS];
    const int tid = threadIdx.x;
    const float* x = x0 + (size_t)blockIdx.y*CIN_*HW_;
    u16* xb = xb0 + (size_t)blockIdx.y*HW_*CIN_;
    const int pix0 = blockIdx.x * 128;
#pragma unroll
    for (int r = 0; r < 8; r++) {
        int e = tid + 256*r;               // 2048 items: 64 c x 32 px-groups
        int c = e >> 5, p4 = (e & 31)*4;
        float4 v = *(const float4*)&x[(size_t)c*HW_ + pix0 + p4];
        T[(p4+0)*XTS + c] = f2bits(v.x);
        T[(p4+1)*XTS + c] = f2bits(v.y);
        T[(p4+2)*XTS + c] = f2bits(v.z);
        T[(p4+3)*XTS + c] = f2bits(v.w);
    }
    __syncthreads();
#pragma unroll
    for (int r = 0; r < 4; r++) {
        int e = tid + 256*r;               // 1024 granules: 128 px x 8
        int p = e >> 3, g = e & 7;
        // rows are XTS*2=140B apart; granule addr 8B-aligned -> copy as 2 uint2
        const u16* s = &T[p*XTS + g*8];
        u16* d = &xb[(size_t)(pix0+p)*CIN_ + g*8];
        *(uint2*)&d[0] = *(const uint2*)&s[0];
        *(uint2*)&d[4] = *(const uint2*)&s[4];
    }
}

// ---------------------------------------------------------------------------
// Conv as shift-decomposed GEMM over px-major activations.
// grid (512, B_), block 256.  in: [hw][CI] bf16, out: [hw][128] bf16.
// ---------------------------------------------------------------------------
template<int CI, int KS, int DIL, int PAD>
__global__ __launch_bounds__(256)
void k_conv(const u16* __restrict__ in0, const u16* __restrict__ wT,
            const float* __restrict__ bias, const float* __restrict__ bns,
            const float* __restrict__ bnb, u16* __restrict__ out0)
{
    __shared__ __align__(16) u16 S[128*TSTR];     // 34.8 KB; As|Bs, reused as T
    u16* As = S;
    u16* Bs = S + 128*LSTR;
    const int tid = threadIdx.x, lane = tid & 63, wave = tid >> 6;
    const int wm = wave & 1, wn_ = wave >> 1;
    const u16* in = in0 + (size_t)blockIdx.y*HW_*CI;
    u16* out = out0 + (size_t)blockIdx.y*HW_*C_;
    const int pix0 = blockIdx.x * 128;
    const int y = pix0 >> 10, x0 = pix0 & 1023;

    f32x4 acc[4][4];
    init_bias(acc, bias, wm, lane);

    for (int p = 0; p < KS*KS; p++) {
        int dy = (p/KS)*DIL - PAD, dx = (p%KS)*DIL - PAD;
        int yy = y + dy;
        if (yy < 0 || yy >= H_) continue;          // wave-uniform (tile = one row)
        const u16* srow = in + (size_t)yy*W_*CI;
        for (int kc = 0; kc < CI/32; kc++) {
            stage_A(As, wT + p*128*CI, CI, kc*32, tid);
#pragma unroll
            for (int r = 0; r < 2; r++) {
                int e = tid + 256*r;
                int j = e >> 2, g = e & 3;
                int xx = x0 + dx + j;
                uint4 v = make_uint4(0u, 0u, 0u, 0u);
                if ((unsigned)xx < (unsigned)W_)
                    v = *(const uint4*)&srow[(size_t)xx*CI + kc*32 + g*8];
                *(uint4*)&Bs[j*LSTR + g*8] = v;
            }
            __syncthreads();
            mfma_step(As, Bs, lane, wm, wn_, acc);
            __syncthreads();
        }
    }
    // Epilogue: bn+lrelu -> LDS transpose tile [px][co] -> vector px-major store
    const int quad = lane >> 4, l15 = lane & 15;
    u16* T = S;
#pragma unroll
    for (int i = 0; i < 4; i++)
#pragma unroll
        for (int r = 0; r < 4; r++) {
            int co = wm*64 + i*16 + quad*4 + r;
            float ss = bns[co], tt = bnb[co];
#pragma unroll
            for (int j = 0; j < 4; j++) {
                float v = lrelu(acc[i][j][r]) * ss + tt;
                T[(wn_*64 + j*16 + l15)*TSTR + co] = f2bits(v);
            }
        }
    __syncthreads();
#pragma unroll
    for (int r = 0; r < 8; r++) {
        int e = tid + 256*r;
        int px = e >> 4, g = e & 15;
        *(uint4*)&out[(size_t)(pix0+px)*C_ + g*8] = *(const uint4*)&T[px*TSTR + g*8];
    }
}

// ---------------------------------------------------------------------------
// resA = bn3(lrelu(c5_w@[A1;A2;A3] + c5_b)) + lrelu(c1_w@x + c1_b)  (fp32 out)
// Inputs xb/A1/A2/A3 in px-major layout; output stays [C][HW] fp32 (required).
// ---------------------------------------------------------------------------
__global__ __launch_bounds__(256)
void k_resA(const u16* __restrict__ xb0, const u16* __restrict__ a10,
            const u16* __restrict__ a20, const u16* __restrict__ a30,
            const u16* __restrict__ wc1, const float* __restrict__ c1b,
            const u16* __restrict__ wc5, const float* __restrict__ c5b,
            const float* __restrict__ s3, const float* __restrict__ b3,
            float* __restrict__ out0)
{
    __shared__ __align__(16) u16 As[128*LSTR];
    __shared__ __align__(16) u16 Bs[128*LSTR];
    const int tid = threadIdx.x, lane = tid & 63, wave = tid >> 6;
    const int wm = wave & 1, wn_ = wave >> 1;
    const int b = blockIdx.y;
    const u16* xb = xb0 + (size_t)b*HW_*CIN_;
    const u16* aa[3] = { a10 + (size_t)b*HW_*C_, a20 + (size_t)b*HW_*C_, a30 + (size_t)b*HW_*C_ };
    float* out = out0 + (size_t)b*C_*HW_;
    const int pix0 = blockIdx.x * 128;
    const int quad = lane >> 4, l15 = lane & 15;

    // shortcut: K=64 over xb
    f32x4 acc[4][4];
    init_bias(acc, c1b, wm, lane);
    for (int kc = 0; kc < 2; kc++) {
        stage_A(As, wc1, 64, kc*32, tid);
        stage_B_pm(Bs, xb + (size_t)pix0*CIN_, CIN_, kc, tid);
        __syncthreads();
        mfma_step(As, Bs, lane, wm, wn_, acc);
        __syncthreads();
    }
    float sc[4][4][4];
#pragma unroll
    for (int i = 0; i < 4; i++)
#pragma unroll
        for (int j = 0; j < 4; j++)
#pragma unroll
            for (int r = 0; r < 4; r++) sc[i][j][r] = lrelu(acc[i][j][r]);

    // main: K=384 over [A1;A2;A3]
    init_bias(acc, c5b, wm, lane);
    for (int s = 0; s < 3; s++) {
        const u16* src = aa[s] + (size_t)pix0*C_;
        for (int kc = 0; kc < 4; kc++) {
            stage_A(As, wc5, 384, s*128 + kc*32, tid);
            stage_B_pm(Bs, src, C_, kc, tid);
            __syncthreads();
            mfma_step(As, Bs, lane, wm, wn_, acc);
            __syncthreads();
        }
    }
#pragma unroll
    for (int i = 0; i < 4; i++)
#pragma unroll
        for (int r = 0; r < 4; r++) {
            int co = wm*64 + i*16 + quad*4 + r;
            float ss = s3[co], tt = b3[co];
#pragma unroll
            for (int j = 0; j < 4; j++) {
                float v = lrelu(acc[i][j][r]) * ss + tt + sc[i][j][r];
                out[co*HW_ + pix0 + wn_*64 + j*16 + l15] = v;
            }
        }
}

// ---------------------------------------------------------------------------
// Fused 3-layer pointwise MLP: h = relu(bn(W3 relu(bn(W2 relu(bn(W1 resA)))))).
// One block owns 128 pixels end-to-end; inter-layer activations in LDS.
// Output h stays channel-major [C][HW] (k_yfused wants x-contiguous rows).
// ---------------------------------------------------------------------------
__global__ __launch_bounds__(256)
void k_pw3(const float* __restrict__ in0, const u16* __restrict__ w,
           const float* __restrict__ pb, const float* __restrict__ ps,
           const float* __restrict__ pbb, u16* __restrict__ out0)
{
    __shared__ __align__(16) u16 As[128*LSTR];
    __shared__ __align__(16) u16 B0[128*PSTR];
    __shared__ __align__(16) u16 B1[128*PSTR];
    const int tid = threadIdx.x, lane = tid & 63, wave = tid >> 6;
    const int wm = wave & 1, wn_ = wave >> 1;
    const int b = blockIdx.y;
    const float* in = in0 + (size_t)b*C_*HW_;
    u16* out = out0 + (size_t)b*C_*HW_;
    const int pix0 = blockIdx.x * 128;
    const int quad = lane >> 4, l15 = lane & 15;

    // Stage B0 [pix][k] from fp32 resA (vector loads along pix, scatter to LDS)
    for (int e = tid; e < 128*32; e += 256) {
        int kk = e >> 5, j4 = (e & 31)*4;
        float4 v = *(const float4*)&in[kk*HW_ + pix0 + j4];
        u16* d = &B0[j4*PSTR + kk];
        d[0]      = f2bits(v.x);
        d[PSTR]   = f2bits(v.y);
        d[2*PSTR] = f2bits(v.z);
        d[3*PSTR] = f2bits(v.w);
    }

    u16* Bc = B0;
    u16* Bn = B1;
#pragma unroll
    for (int L = 0; L < 3; L++) {
        f32x4 acc[4][4];
        init_bias(acc, pb + L*128, wm, lane);
        for (int kc = 0; kc < 4; kc++) {
            stage_A(As, w + L*16384, 128, kc*32, tid);
            __syncthreads();                       // As + (Bc writes) visible
            mfma_step_s(As, Bc, PSTR, kc*32, lane, wm, wn_, acc);
            __syncthreads();                       // done reading As
        }
        const float* ss = ps + L*128;
        const float* tt = pbb + L*128;
        if (L < 2) {
#pragma unroll
            for (int i = 0; i < 4; i++)
#pragma unroll
                for (int r = 0; r < 4; r++) {
                    int co = wm*64 + i*16 + quad*4 + r;
                    float s1 = ss[co], t1 = tt[co];
#pragma unroll
                    for (int j = 0; j < 4; j++) {
                        float v = relu(acc[i][j][r] * s1 + t1);
                        Bn[(wn_*64 + j*16 + l15)*PSTR + co] = f2bits(v);
                    }
                }
            u16* t = Bc; Bc = Bn; Bn = t;
        } else {
#pragma unroll
            for (int i = 0; i < 4; i++)
#pragma unroll
                for (int r = 0; r < 4; r++) {
                    int co = wm*64 + i*16 + quad*4 + r;
                    float s1 = ss[co], t1 = tt[co];
#pragma unroll
                    for (int j = 0; j < 4; j++) {
                        float v = relu(acc[i][j][r] * s1 + t1);
                        out[co*HW_ + pix0 + wn_*64 + j*16 + l15] = f2bits(v);
                    }
                }
        }
    }
}

// ---------------------------------------------------------------------------
// WeightNet: xyz fp32 -> bf16 [16,25,H2,W2] per batch.
// ---------------------------------------------------------------------------
__global__ __launch_bounds__(256)
void wn_kernel(const float* __restrict__ xyz0,
               const float* __restrict__ w1w, const float* __restrict__ w1b,
               const float* __restrict__ w2w, const float* __restrict__ w2b,
               const float* __restrict__ w3w, const float* __restrict__ w3b,
               const float* __restrict__ s1, const float* __restrict__ bb1,
               const float* __restrict__ s2, const float* __restrict__ bb2,
               const float* __restrict__ s3, const float* __restrict__ bb3,
               u16* __restrict__ out0)
{
    const float* xyz = xyz0 + (size_t)blockIdx.y*3*HW_;
    u16* out = out0 + (size_t)blockIdx.y*400*HW2_;
    int idx = blockIdx.x*256 + threadIdx.x;
    int j = idx & (W2_-1); int t = idx >> 9;
    int i = t & (H2_-1);   int k = t >> 5;
    int kh = k / 5, kw = k - kh*5;
    int yy = 2*i + kh - 2, xx = 2*j + kw - 2;
    bool inr = (yy >= 0 && yy < H_ && xx >= 0 && xx < W_);

    float g[3];
#pragma unroll
    for (int c = 0; c < 3; c++) {
        float ctr = xyz[c*HW_ + (2*i)*W_ + 2*j];
        float v = inr ? xyz[c*HW_ + yy*W_ + xx] : 0.f;
        g[c] = v - ctr;
    }
    float a1[8];
#pragma unroll
    for (int n = 0; n < 8; n++) {
        float v = w1b[n];
#pragma unroll
        for (int c = 0; c < 3; c++) v += w1w[n*3 + c] * g[c];
        a1[n] = relu(v * s1[n] + bb1[n]);
    }
    float a2[8];
#pragma unroll
    for (int n = 0; n < 8; n++) {
        float v = w2b[n];
#pragma unroll
        for (int m = 0; m < 8; m++) v += w2w[n*8 + m] * a1[m];
        a2[n] = relu(v * s2[n] + bb2[n]);
    }
#pragma unroll
    for (int n = 0; n < 16; n++) {
        float v = w3b[n];
#pragma unroll
        for (int m = 0; m < 8; m++) v += w3w[n*8 + m] * a2[m];
        v = relu(v * s3[n] + bb3[n]);
        out[(n*25 + k)*HW2_ + i*W2_ + j] = f2bits(v);
    }
}

// ---------------------------------------------------------------------------
// Fused ycompute + linear head:
//   y[px][c*16+n] = sum_k unf(h)[c][k][px] * wn[n][k][px]     (bf16, LDS only)
//   resB[co][px]  = relu(bn(sum_{c,n} lin_w[co][c*16+n] * y[px][c*16+n] + b))
// grid (32 i2 * 8 jt, B_), block 512.  Per c0-chunk (8 ch): y sub-tile
// [64 px][128 k] in LDS -> 4 MFMA K-steps vs lin_w K-slice.  16 chunks = K=2048.
// Phase-1 lanes: (n = tid&15 fast, pxq = tid>>4) -> 16-way broadcast slab reads.
// NOTE: no min-blocks launch_bounds arg — (512,4) forced a 64-VGPR cap and
// catastrophic scratch spills (R3: 258MB fetch / 347MB write of scratch).
// LDS (74.5KB -> 2 blocks/CU) already steers the allocator to the 128-VGPR class.
// ---------------------------------------------------------------------------
__global__ __launch_bounds__(512)
void k_yfused(const u16* __restrict__ h0, const u16* __restrict__ wn0,
              const u16* __restrict__ w, const float* __restrict__ bias,
              const float* __restrict__ bns, const float* __restrict__ bnb,
              float* __restrict__ out0)
{
    __shared__ __align__(16) float slab[40*148];   // 23.7 KB (8 cc * 5 rr rows)
    __shared__ __align__(16) u16 As[128*PSTR];     // 34.8 KB (lin_w K-slice 128)
    __shared__ __align__(16) u16 Bs[64*PSTR];      // 17.4 KB (y sub-tile)
    const int tid = threadIdx.x;
    const int bx = blockIdx.x;
    const int j0 = (bx & 7) * 64;
    const int i2 = bx >> 3;
    const int b  = blockIdx.y;
    const u16* h  = h0  + (size_t)b*C_*HW_;
    const u16* wn = wn0 + (size_t)b*400*HW2_;
    float* out = out0 + (size_t)b*C_*HW2_;

    // phase-1 roles: n fast (broadcast group), pxq = px-pair index
    const int n = tid & 15, pxq = tid >> 4;        // pxq 0..31
    // phase-2 roles
    const int lane = tid & 63, wave = tid >> 6;
    const int wm4 = wave & 3, wnp = wave >> 2;     // 4x32 co, 2x32 px
    const int quad = lane >> 4, l15 = lane & 15;

    // wn for this thread's (n, px-pair): 25 taps f32 in regs (50 VGPR)
    float wnreg[25][2];
    {
        const u16* wb = wn + (n*25)*HW2_ + i2*W2_ + j0 + pxq*2;
#pragma unroll
        for (int k = 0; k < 25; k++) {
            u32 t = *(const u32*)(wb + k*HW2_);
            wnreg[k][0] = bits2f((u16)(t & 0xffff));
            wnreg[k][1] = bits2f((u16)(t >> 16));
        }
    }

    f32x4 acc[2][2];
#pragma unroll
    for (int i = 0; i < 2; i++)
#pragma unroll
        for (int r = 0; r < 4; r++) {
            float bv = bias[wm4*32 + i*16 + quad*4 + r];
            acc[i][0][r] = bv;
            acc[i][1][r] = bv;
        }

    for (int c0 = 0; c0 < 128; c0 += 8) {
        __syncthreads();                           // prev mfma + y-compute done
        // Fill slab: 8 cc x 5 rr x 18 uint4-groups (identical math to before)
        for (int e = tid; e < 720; e += 512) {
            int cc = e / 90, rem = e - cc*90;
            int rr = rem / 18, g = rem - rr*18;
            int yy = 2*i2 + rr - 2;
            int xs0 = 2*j0 - 8 + 8*g;              // 16B-aligned global offset
            float f[8];
            if ((unsigned)yy < (unsigned)H_ && (unsigned)xs0 <= (unsigned)(W_-8)) {
                uint4 v = *(const uint4*)&h[(c0+cc)*HW_ + yy*W_ + xs0];
                f[0] = bits2f((u16)(v.x & 0xffff)); f[1] = bits2f((u16)(v.x >> 16));
                f[2] = bits2f((u16)(v.y & 0xffff)); f[3] = bits2f((u16)(v.y >> 16));
                f[4] = bits2f((u16)(v.z & 0xffff)); f[5] = bits2f((u16)(v.z >> 16));
                f[6] = bits2f((u16)(v.w & 0xffff)); f[7] = bits2f((u16)(v.w >> 16));
            } else if ((unsigned)yy < (unsigned)H_) {
#pragma unroll
                for (int m = 0; m < 8; m++) {
                    int xs = xs0 + m;
                    f[m] = ((unsigned)xs < (unsigned)W_)
                         ? bits2f(h[(c0+cc)*HW_ + yy*W_ + xs]) : 0.f;
                }
            } else {
#pragma unroll
                for (int m = 0; m < 8; m++) f[m] = 0.f;
            }
            float* d = &slab[(cc*5 + rr)*148 + 2 + 8*g];
            *(float2*)(d+0) = make_float2(f[0], f[1]);
            *(float2*)(d+2) = make_float2(f[2], f[3]);
            *(float2*)(d+4) = make_float2(f[4], f[5]);
            *(float2*)(d+6) = make_float2(f[6], f[7]);
        }
        // Stage lin_w K-slice [128 co][128 k] (cols c0*16 .. +128)
#pragma unroll
        for (int r = 0; r < 4; r++) {
            int e = tid + 512*r;                   // 2048 granules
            int co = e >> 4, g = e & 15;
            *(uint4*)&As[co*PSTR + g*8] = *(const uint4*)&w[co*2048 + c0*16 + g*8];
        }
        __syncthreads();                           // slab + As ready
        // y-compute into Bs [px][cc*16+n]
#pragma unroll 2
        for (int cc = 0; cc < 8; cc++) {
            float yv0 = 0.f, yv1 = 0.f;
#pragma unroll
            for (int rr = 0; rr < 5; rr++) {
                const float* fr = &slab[(cc*5 + rr)*148 + 8 + 4*pxq];
                float4 A  = *(const float4*)fr;
                float4 Bv = *(const float4*)(fr + 4);
                yv0 += A.x*wnreg[rr*5+0][0] + A.y*wnreg[rr*5+1][0]
                     + A.z*wnreg[rr*5+2][0] + A.w*wnreg[rr*5+3][0]
                     + Bv.x*wnreg[rr*5+4][0];
                yv1 += A.z*wnreg[rr*5+0][1] + A.w*wnreg[rr*5+1][1]
                     + Bv.x*wnreg[rr*5+2][1] + Bv.y*wnreg[rr*5+3][1]
                     + Bv.z*wnreg[rr*5+4][1];
            }
            Bs[(2*pxq)  *PSTR + cc*16 + n] = f2bits(yv0);
            Bs[(2*pxq+1)*PSTR + cc*16 + n] = f2bits(yv1);
        }
        __syncthreads();                           // Bs ready
#pragma unroll
        for (int kc = 0; kc < 4; kc++) {
            bf16x8 a0 = *(const bf16x8*)&As[(wm4*32 +  0 + l15)*PSTR + kc*32 + quad*8];
            bf16x8 a1 = *(const bf16x8*)&As[(wm4*32 + 16 + l15)*PSTR + kc*32 + quad*8];
            bf16x8 b0 = *(const bf16x8*)&Bs[(wnp*32 +  0 + l15)*PSTR + kc*32 + quad*8];
            bf16x8 b1 = *(const bf16x8*)&Bs[(wnp*32 + 16 + l15)*PSTR + kc*32 + quad*8];
            acc[0][0] = __builtin_amdgcn_mfma_f32_16x16x32_bf16(a0, b0, acc[0][0], 0, 0, 0);
            acc[0][1] = __builtin_amdgcn_mfma_f32_16x16x32_bf16(a0, b1, acc[0][1], 0, 0, 0);
            acc[1][0] = __builtin_amdgcn_mfma_f32_16x16x32_bf16(a1, b0, acc[1][0], 0, 0, 0);
            acc[1][1] = __builtin_amdgcn_mfma_f32_16x16x32_bf16(a1, b1, acc[1][1], 0, 0, 0);
        }
    }
    // epilogue: bn + relu -> fp32 resB
#pragma unroll
    for (int i = 0; i < 2; i++)
#pragma unroll
        for (int r = 0; r < 4; r++) {
            int co = wm4*32 + i*16 + quad*4 + r;
            float ss = bns[co], tt = bnb[co];
#pragma unroll
            for (int j = 0; j < 2; j++) {
                float v = relu(acc[i][j][r] * ss + tt);
                out[co*HW2_ + i2*W2_ + j0 + wnp*32 + j*16 + l15] = v;
            }
        }
}

// ---------------------------------------------------------------------------
// Weight transform: fp32 -> bf16 g_wts (k-contiguous layouts).
// ---------------------------------------------------------------------------
__global__ __launch_bounds__(256)
void k_wtrans(const float* __restrict__ c2w, const float* __restrict__ c3w,
              const float* __restrict__ c4w, const float* __restrict__ c5w,
              const float* __restrict__ c1w, const float* __restrict__ pw,
              const float* __restrict__ linw)
{
    int i = blockIdx.x*256 + threadIdx.x;
    if (i >= WTS_TOT) return;
    float v;
    if (i < OFF_C3) {
        int p = i / 8192, rem = i - p*8192;
        int co = rem >> 6, ci = rem & 63;
        v = c2w[(co*64 + ci)*9 + p];
    } else if (i < OFF_C4) {
        int t = i - OFF_C3;
        int p = t / 16384, rem = t - p*16384;
        int co = rem >> 7, ci = rem & 127;
        v = c3w[(co*128 + ci)*9 + p];
    } else if (i < OFF_C5) {
        int t = i - OFF_C4;
        int p = t / 16384, rem = t - p*16384;
        int co = rem >> 7, ci = rem & 127;
        v = c4w[(co*128 + ci)*4 + p];
    } else if (i < OFF_C1)  v = c5w[i - OFF_C5];
    else if (i < OFF_PW)    v = c1w[i - OFF_C1];
    else if (i < OFF_LIN)   v = pw[i - OFF_PW];
    else                    v = linw[i - OFF_LIN];
    g_wts[i] = f2bits(v);
}

// ---------------------------------------------------------------------------
extern "C" void kernel_launch(void* const* d_in, const int* in_sizes, int n_in,
                              void* d_out, int out_size, void* d_ws, size_t ws_size,
                              hipStream_t stream)
{
    const float* x     = (const float*)d_in[0];
    const float* xyz   = (const float*)d_in[1];
    const float* c1_w  = (const float*)d_in[2];
    const float* c1_b  = (const float*)d_in[3];
    const float* c2_w  = (const float*)d_in[4];
    const float* c2_b  = (const float*)d_in[5];
    const float* c3_w  = (const float*)d_in[6];
    const float* c3_b  = (const float*)d_in[7];
    const float* c4_w  = (const float*)d_in[8];
    const float* c4_b  = (const float*)d_in[9];
    const float* c5_w  = (const float*)d_in[10];
    const float* c5_b  = (const float*)d_in[11];
    const float* rbn_s = (const float*)d_in[12];
    const float* rbn_b = (const float*)d_in[13];
    const float* p_w   = (const float*)d_in[14];
    const float* p_b   = (const float*)d_in[15];
    const float* pbn_s = (const float*)d_in[16];
    const float* pbn_b = (const float*)d_in[17];
    const float* lin_w = (const float*)d_in[18];
    const float* lin_b = (const float*)d_in[19];
    const float* w1_w  = (const float*)d_in[20];
    const float* w1_b  = (const float*)d_in[21];
    const float* w2_w  = (const float*)d_in[22];
    const float* w2_b  = (const float*)d_in[23];
    const float* w3_w  = (const float*)d_in[24];
    const float* w3_b  = (const float*)d_in[25];
    const float* wbn1_s = (const float*)d_in[26];
    const float* wbn1_b = (const float*)d_in[27];
    const float* wbn2_s = (const float*)d_in[28];
    const float* wbn2_b = (const float*)d_in[29];
    const float* wbn3_s = (const float*)d_in[30];
    const float* wbn3_b = (const float*)d_in[31];

    float* outB = (float*)d_out;                     // [2,128,32,512] fp32
    float* outA = outB + (size_t)B_*C_*HW2_;         // [2,128,64,1024] fp32

    u16 *wts, *b1, *b2, *b3, *xb;
    { void* p; hipGetSymbolAddress(&p, HIP_SYMBOL(g_wts)); wts = (u16*)p; }
    { void* p; hipGetSymbolAddress(&p, HIP_SYMBOL(g_b1));  b1  = (u16*)p; }
    { void* p; hipGetSymbolAddress(&p, HIP_SYMBOL(g_b2));  b2  = (u16*)p; }
    { void* p; hipGetSymbolAddress(&p, HIP_SYMBOL(g_b3));  b3  = (u16*)p; }
    { void* p; hipGetSymbolAddress(&p, HIP_SYMBOL(g_xb));  xb  = (u16*)p; }

    dim3 blk(256);

    k_wtrans<<<dim3((WTS_TOT + 255)/256), blk, 0, stream>>>(c2_w, c3_w, c4_w, c5_w,
                                                            c1_w, p_w, lin_w);
    k_xtrans<<<dim3(512, B_), blk, 0, stream>>>(x, xb);
    k_conv<64,3,1,1><<<dim3(512, B_), blk, 0, stream>>>(xb, wts+OFF_C2, c2_b,
                                                        rbn_s, rbn_b, b1);
    k_conv<128,3,2,2><<<dim3(512, B_), blk, 0, stream>>>(b1, wts+OFF_C3, c3_b,
                                                         rbn_s+128, rbn_b+128, b2);
    k_conv<128,2,2,1><<<dim3(512, B_), blk, 0, stream>>>(b2, wts+OFF_C4, c4_b,
                                                         rbn_s+256, rbn_b+256, b3);
    k_resA<<<dim3(512, B_), blk, 0, stream>>>(xb, b1, b2, b3, wts+OFF_C1, c1_b,
                                              wts+OFF_C5, c5_b, rbn_s+384, rbn_b+384, outA);
    k_pw3<<<dim3(512, B_), blk, 0, stream>>>(outA, wts+OFF_PW, p_b, pbn_s, pbn_b, b1);
    wn_kernel<<<dim3(1600, B_), blk, 0, stream>>>(xyz, w1_w, w1_b, w2_w, w2_b, w3_w, w3_b,
                                                  wbn1_s, wbn1_b, wbn2_s, wbn2_b,
                                                  wbn3_s, wbn3_b, b2);
    k_yfused<<<dim3(256, B_), dim3(512), 0, stream>>>(b1, b2, wts+OFF_LIN, lin_b,
                                                      pbn_s+384, pbn_b+384, outB);
}